// Round 1
// baseline (1549.528 us; speedup 1.0000x reference)
//
#include <hip/hip_runtime.h>
#include <hip/hip_bf16.h>

typedef unsigned short u16;
typedef __bf16 bf16x8 __attribute__((ext_vector_type(8)));
typedef float f32x4 __attribute__((ext_vector_type(4)));

#define DIMC  2048
#define NH    16
#define HD    128
#define BSZ   2
#define SEQ   4096
#define MTOK  (BSZ*SEQ)   /* 8192 tokens */

__device__ __forceinline__ u16 f2bf(float f) {
  unsigned u = __float_as_uint(f);
  u += 0x7fff + ((u >> 16) & 1);   // RTNE
  return (u16)(u >> 16);
}
__device__ __forceinline__ float bf2f(u16 b) {
  return __uint_as_float(((unsigned)b) << 16);
}

__device__ __forceinline__ void gload_lds16(const void* g, void* l) {
  __builtin_amdgcn_global_load_lds(
      (const __attribute__((address_space(1))) void*)g,
      (__attribute__((address_space(3))) void*)l, 16, 0, 0);
}

// ---------------- cast f32 -> bf16 ----------------
__global__ __launch_bounds__(256) void cast_bf16_k(const float* __restrict__ in,
                                                   u16* __restrict__ out, int n) {
  int i = (blockIdx.x * 256 + threadIdx.x) * 4;
  if (i >= n) return;
  float4 v = *(const float4*)(in + i);
  ushort4 o;
  o.x = f2bf(v.x); o.y = f2bf(v.y); o.z = f2bf(v.z); o.w = f2bf(v.w);
  *(ushort4*)(out + i) = o;
}

// ---------------- GEMM: C[m,n] = sum_k A[m,k]*Bt[n,k] + bias[n] ----------------
// 128x128 tile, BK=64, 256 threads (4 waves, 2x2 of 64x64), m97 structure.
template<bool OUT_F32>
__global__ __launch_bounds__(256) void gemm_bt_k(
    const u16* __restrict__ A, const u16* __restrict__ Bt,
    const float* __restrict__ bias, void* __restrict__ Cout,
    int Ndim, int Kdim) {
  __shared__ __align__(16) u16 As[128][64];
  __shared__ __align__(16) u16 Bs[128][64];
  const int tid = threadIdx.x;
  const int lane = tid & 63, wid = tid >> 6;
  const int wr = wid >> 1, wc = wid & 1;
  const int l15 = lane & 15, lg = lane >> 4;
  const int bm = blockIdx.y * 128;
  const int bn = blockIdx.x * 128;

  f32x4 acc[4][4];
#pragma unroll
  for (int i = 0; i < 4; i++)
#pragma unroll
    for (int j = 0; j < 4; j++) acc[i][j] = f32x4{0.f, 0.f, 0.f, 0.f};

  for (int kt = 0; kt < Kdim; kt += 64) {
#pragma unroll
    for (int it = 0; it < 4; ++it) {
      int c = it * 256 + tid;
      int rr = c >> 3, cc = c & 7;
      gload_lds16(A + (size_t)(bm + rr) * Kdim + kt + cc * 8, (u16*)As + c * 8);
      gload_lds16(Bt + (size_t)(bn + rr) * Kdim + kt + cc * 8, (u16*)Bs + c * 8);
    }
    __syncthreads();
#pragma unroll
    for (int ks = 0; ks < 2; ++ks) {
      bf16x8 af[4], bfr[4];
#pragma unroll
      for (int i = 0; i < 4; i++)
        af[i] = *(const bf16x8*)&As[wr * 64 + i * 16 + l15][ks * 32 + lg * 8];
#pragma unroll
      for (int j = 0; j < 4; j++)
        bfr[j] = *(const bf16x8*)&Bs[wc * 64 + j * 16 + l15][ks * 32 + lg * 8];
#pragma unroll
      for (int i = 0; i < 4; i++)
#pragma unroll
        for (int j = 0; j < 4; j++)
          acc[i][j] = __builtin_amdgcn_mfma_f32_16x16x32_bf16(af[i], bfr[j], acc[i][j], 0, 0, 0);
    }
    __syncthreads();
  }
  // epilogue: C/D layout col=lane&15, row=(lane>>4)*4+reg
#pragma unroll
  for (int j = 0; j < 4; j++) {
    const int cj = bn + wc * 64 + j * 16 + l15;
    const float bv = bias[cj];
#pragma unroll
    for (int i = 0; i < 4; i++) {
      const int r0 = bm + wr * 64 + i * 16 + lg * 4;
#pragma unroll
      for (int r = 0; r < 4; r++) {
        float v = acc[i][j][r] + bv;
        if (OUT_F32) ((float*)Cout)[(size_t)(r0 + r) * Ndim + cj] = v;
        else         ((u16*)Cout)[(size_t)(r0 + r) * Ndim + cj] = f2bf(v);
      }
    }
  }
}

// ---------------- fused RMSNorm + RoPE (in-place on q,k; bf16 storage) ----------------
__global__ __launch_bounds__(256) void rmsrope_k(
    u16* __restrict__ qk, const float* __restrict__ gq, const float* __restrict__ gk,
    const float* __restrict__ freqs) {
  const int t = blockIdx.x;        // token
  const int s = t & (SEQ - 1);
  const int tid = threadIdx.x;
  __shared__ float red[8];

  for (int which = 0; which < 2; ++which) {
    u16* row = qk + (size_t)which * ((size_t)MTOK * DIMC) + (size_t)t * DIMC;
    const float* g = which ? gk : gq;
    uint4 raw = *(const uint4*)(row + tid * 8);
    const u16* rb = (const u16*)&raw;
    float v[8], ss = 0.f;
#pragma unroll
    for (int e = 0; e < 8; e++) { v[e] = bf2f(rb[e]); ss += v[e] * v[e]; }
#pragma unroll
    for (int m = 1; m < 64; m <<= 1) ss += __shfl_xor(ss, m);
    if ((tid & 63) == 0) red[which * 4 + (tid >> 6)] = ss;
    __syncthreads();
    float tot = red[which * 4] + red[which * 4 + 1] + red[which * 4 + 2] + red[which * 4 + 3];
    float rms = rsqrtf(tot * (1.0f / (float)DIMC) + 1e-6f);
    const int ch0 = tid * 8;
    const int d0 = ch0 & (HD - 1);
    u16 ob[8];
#pragma unroll
    for (int p = 0; p < 4; p++) {
      float fr = freqs[s * (HD / 2) + (d0 >> 1) + p];
      float cs = cosf(fr), sn = sinf(fr);
      float e = v[2 * p] * rms * g[ch0 + 2 * p];
      float o = v[2 * p + 1] * rms * g[ch0 + 2 * p + 1];
      ob[2 * p]     = f2bf(e * cs - o * sn);
      ob[2 * p + 1] = f2bf(e * sn + o * cs);
    }
    *(uint4*)(row + tid * 8) = *(const uint4*)ob;
    __syncthreads();
  }
}

// ---------------- transpose V: v[t][c] -> vT[(b*2048+c)][s] ----------------
__global__ __launch_bounds__(256) void vtrans_k(const u16* __restrict__ v, u16* __restrict__ vT) {
  __shared__ u16 tile[64][72];
  const int s0 = blockIdx.x * 64, c0 = blockIdx.y * 64, b = blockIdx.z;
  const int tid = threadIdx.x;
  const int rr = tid >> 3, cc8 = (tid & 7) * 8;
#pragma unroll
  for (int it = 0; it < 2; ++it) {
    int si = it * 32 + rr;
    uint4 d = *(const uint4*)(v + ((size_t)(b * SEQ + s0 + si)) * DIMC + c0 + cc8);
    const u16* dp = (const u16*)&d;
#pragma unroll
    for (int e = 0; e < 8; e++) tile[si][cc8 + e] = dp[e];
  }
  __syncthreads();
#pragma unroll
  for (int it = 0; it < 2; ++it) {
    int ci = it * 32 + rr;
    u16 buf[8];
#pragma unroll
    for (int e = 0; e < 8; e++) buf[e] = tile[cc8 + e][ci];
    *(uint4*)(vT + ((size_t)(b * DIMC + c0 + ci)) * SEQ + s0 + cc8) = *(const uint4*)buf;
  }
}

// ---------------- flash attention ----------------
// grid: (SEQ/64, B*NH). 4 waves x 16 q-rows. KV tile = 64. vT layout [b*2048+c][s].
__global__ __launch_bounds__(256) void attn_k(
    const u16* __restrict__ qbuf, const u16* __restrict__ kbuf,
    const u16* __restrict__ vT, u16* __restrict__ obuf) {
  const int bh = blockIdx.y, b = bh >> 4, h = bh & 15;
  const int q0 = blockIdx.x * 64;
  const int tid = threadIdx.x, lane = tid & 63, wid = tid >> 6;
  const int l15 = lane & 15, lg = lane >> 4;
  const float SCALE_L2E = 0.08838834764831845f * 1.4426950408889634f;

  __shared__ __align__(16) u16 Ks[64 * 128];
  __shared__ __align__(16) u16 Vs[128 * 64];
  __shared__ __align__(16) u16 Ps[4][16 * 64];

  const size_t qkbase = (size_t)(b * SEQ) * DIMC + h * HD;
  const u16* Qp = qbuf + qkbase;
  const u16* Kp = kbuf + qkbase;
  const u16* Vp = vT + (size_t)(b * DIMC + h * HD) * SEQ;

  const int qrow = q0 + wid * 16 + l15;
  bf16x8 qf[4];
#pragma unroll
  for (int ks = 0; ks < 4; ++ks)
    qf[ks] = *(const bf16x8*)(Qp + (size_t)qrow * DIMC + ks * 32 + lg * 8);

  float mcur[4], lcur[4];
#pragma unroll
  for (int r = 0; r < 4; r++) { mcur[r] = -1e30f; lcur[r] = 0.f; }
  f32x4 accO[8];
#pragma unroll
  for (int dj = 0; dj < 8; dj++) accO[dj] = f32x4{0.f, 0.f, 0.f, 0.f};

  for (int kv0 = 0; kv0 < SEQ; kv0 += 64) {
    // stage K tile (64x128) + V tile (128x64), XOR-swizzled via global source
#pragma unroll
    for (int it = 0; it < 4; ++it) {
      int c = it * 256 + tid;
      { int rr = c >> 4, cc = c & 15;
        gload_lds16(Kp + (size_t)(kv0 + rr) * DIMC + (cc ^ (rr & 7)) * 8, (u16*)Ks + c * 8); }
      { int rr = c >> 3, cc = c & 7;
        gload_lds16(Vp + (size_t)rr * SEQ + kv0 + (cc ^ (rr & 7)) * 8, (u16*)Vs + c * 8); }
    }
    __syncthreads();

    // QK^T: S[q][k], q=wave's 16 rows
    f32x4 sc[4];
#pragma unroll
    for (int kj = 0; kj < 4; kj++) {
      sc[kj] = f32x4{0.f, 0.f, 0.f, 0.f};
      int row = kj * 16 + l15;
#pragma unroll
      for (int ks = 0; ks < 4; ks++) {
        const bf16x8 bfr = *(const bf16x8*)((const char*)Ks + row * 256 +
                                            ((ks * 64 + lg * 16) ^ ((row & 7) << 4)));
        sc[kj] = __builtin_amdgcn_mfma_f32_16x16x32_bf16(qf[ks], bfr, sc[kj], 0, 0, 0);
      }
    }
    // scale into exp2 domain
#pragma unroll
    for (int kj = 0; kj < 4; kj++)
#pragma unroll
      for (int r = 0; r < 4; r++) sc[kj][r] *= SCALE_L2E;

    // online softmax (rows q = lg*4+r, cols k across l15 lanes & kj)
    float rmax[4];
#pragma unroll
    for (int r = 0; r < 4; r++)
      rmax[r] = fmaxf(fmaxf(sc[0][r], sc[1][r]), fmaxf(sc[2][r], sc[3][r]));
#pragma unroll
    for (int m = 1; m < 16; m <<= 1)
#pragma unroll
      for (int r = 0; r < 4; r++) rmax[r] = fmaxf(rmax[r], __shfl_xor(rmax[r], m));

    float alpha[4], rsum[4];
    float ps[4][4];
#pragma unroll
    for (int r = 0; r < 4; r++) {
      float mn = fmaxf(mcur[r], rmax[r]);
      alpha[r] = exp2f(mcur[r] - mn);
      mcur[r] = mn;
      rsum[r] = 0.f;
    }
#pragma unroll
    for (int kj = 0; kj < 4; kj++)
#pragma unroll
      for (int r = 0; r < 4; r++) {
        float p = exp2f(sc[kj][r] - mcur[r]);
        ps[kj][r] = p;
        rsum[r] += p;
      }
#pragma unroll
    for (int m = 1; m < 16; m <<= 1)
#pragma unroll
      for (int r = 0; r < 4; r++) rsum[r] += __shfl_xor(rsum[r], m);
#pragma unroll
    for (int r = 0; r < 4; r++) lcur[r] = lcur[r] * alpha[r] + rsum[r];
#pragma unroll
    for (int dj = 0; dj < 8; dj++)
#pragma unroll
      for (int r = 0; r < 4; r++) accO[dj][r] *= alpha[r];

    // write P tile to per-wave LDS (swizzled), re-read as A-fragments
#pragma unroll
    for (int kj = 0; kj < 4; kj++)
#pragma unroll
      for (int r = 0; r < 4; r++) {
        int qr = lg * 4 + r;
        int col = kj * 16 + l15;
        Ps[wid][qr * 64 + (col ^ ((qr & 7) << 3))] = f2bf(ps[kj][r]);
      }
    // PV: O[q][d] += P[q][k] * Vs[d][k]
#pragma unroll
    for (int ks2 = 0; ks2 < 2; ks2++) {
      const bf16x8 pa = *(const bf16x8*)((const char*)Ps[wid] + l15 * 128 +
                                         ((ks2 * 64 + lg * 16) ^ ((l15 & 7) << 4)));
#pragma unroll
      for (int dj = 0; dj < 8; dj++) {
        int row = dj * 16 + l15;
        const bf16x8 vb = *(const bf16x8*)((const char*)Vs + row * 128 +
                                           ((ks2 * 64 + lg * 16) ^ ((row & 7) << 4)));
        accO[dj] = __builtin_amdgcn_mfma_f32_16x16x32_bf16(pa, vb, accO[dj], 0, 0, 0);
      }
    }
    __syncthreads();
  }

  float linv[4];
#pragma unroll
  for (int r = 0; r < 4; r++) linv[r] = 1.0f / lcur[r];
  u16* Op = obuf + (size_t)(b * SEQ + q0 + wid * 16) * DIMC + h * HD;
#pragma unroll
  for (int dj = 0; dj < 8; dj++)
#pragma unroll
    for (int r = 0; r < 4; r++) {
      int rq = lg * 4 + r;
      Op[(size_t)rq * DIMC + dj * 16 + l15] = f2bf(accO[dj][r] * linv[r]);
    }
}

// ---------------- launch ----------------
extern "C" void kernel_launch(void* const* d_in, const int* in_sizes, int n_in,
                              void* d_out, int out_size, void* d_ws, size_t ws_size,
                              hipStream_t stream) {
  const float* x     = (const float*)d_in[0];
  const float* freqs = (const float*)d_in[2];
  const float* wq = (const float*)d_in[3];
  const float* bq = (const float*)d_in[4];
  const float* wk = (const float*)d_in[5];
  const float* bk = (const float*)d_in[6];
  const float* wv = (const float*)d_in[7];
  const float* bv = (const float*)d_in[8];
  const float* wo = (const float*)d_in[9];
  const float* bo = (const float*)d_in[10];
  const float* gq = (const float*)d_in[11];
  const float* gk = (const float*)d_in[12];

  const size_t WS = (size_t)DIMC * DIMC;       // weight elems
  const size_t QS = (size_t)MTOK * DIMC;       // activation elems
  char* ws = (char*)d_ws;
  u16* xb  = (u16*)ws;  ws += QS * 2;
  u16* wb  = (u16*)ws;  ws += 4 * WS * 2;
  u16* qkv = (u16*)ws;  ws += 3 * QS * 2;
  u16* vT  = (u16*)ws;  ws += QS * 2;
  u16* ob  = (u16*)ws;  ws += QS * 2;

  cast_bf16_k<<<(int)(QS / 1024), 256, 0, stream>>>(x, xb, (int)QS);
  cast_bf16_k<<<(int)(WS / 1024), 256, 0, stream>>>(wq, wb + 0 * WS, (int)WS);
  cast_bf16_k<<<(int)(WS / 1024), 256, 0, stream>>>(wk, wb + 1 * WS, (int)WS);
  cast_bf16_k<<<(int)(WS / 1024), 256, 0, stream>>>(wv, wb + 2 * WS, (int)WS);
  cast_bf16_k<<<(int)(WS / 1024), 256, 0, stream>>>(wo, wb + 3 * WS, (int)WS);

  dim3 ggrid(DIMC / 128, MTOK / 128);
  gemm_bt_k<false><<<ggrid, 256, 0, stream>>>(xb, wb + 0 * WS, bq, qkv + 0 * QS, DIMC, DIMC);
  gemm_bt_k<false><<<ggrid, 256, 0, stream>>>(xb, wb + 1 * WS, bk, qkv + 1 * QS, DIMC, DIMC);
  gemm_bt_k<false><<<ggrid, 256, 0, stream>>>(xb, wb + 2 * WS, bv, qkv + 2 * QS, DIMC, DIMC);

  rmsrope_k<<<MTOK, 256, 0, stream>>>(qkv, gq, gk, freqs);
  vtrans_k<<<dim3(SEQ / 64, DIMC / 64, BSZ), 256, 0, stream>>>(qkv + 2 * QS, vT);
  attn_k<<<dim3(SEQ / 64, BSZ * NH), 256, 0, stream>>>(qkv, qkv + 1 * QS, vT, ob);

  gemm_bt_k<true><<<ggrid, 256, 0, stream>>>(ob, wb + 3 * WS, bo, d_out, DIMC, DIMC);
}

// Round 2
// 1032.020 us; speedup vs baseline: 1.5015x; 1.5015x over previous
//
#include <hip/hip_runtime.h>
#include <hip/hip_bf16.h>

typedef unsigned short u16;
typedef __bf16 bf16x8 __attribute__((ext_vector_type(8)));
typedef float f32x4 __attribute__((ext_vector_type(4)));

#define DIMC  2048
#define NH    16
#define HD    128
#define BSZ   2
#define SEQ   4096
#define MTOK  (BSZ*SEQ)   /* 8192 tokens */

// scale * log2(e): folded into Q at rmsrope time
#define SCALE_L2E (0.08838834764831845f * 1.4426950408889634f)

__device__ __forceinline__ u16 f2bf(float f) {
  unsigned u = __float_as_uint(f);
  u += 0x7fff + ((u >> 16) & 1);   // RTNE
  return (u16)(u >> 16);
}
__device__ __forceinline__ float bf2f(u16 b) {
  return __uint_as_float(((unsigned)b) << 16);
}

__device__ __forceinline__ void gload_lds16(const void* g, void* l) {
  __builtin_amdgcn_global_load_lds(
      (const __attribute__((address_space(1))) void*)g,
      (__attribute__((address_space(3))) void*)l, 16, 0, 0);
}

// ---------------- cast f32 -> bf16 ----------------
__global__ __launch_bounds__(256) void cast_bf16_k(const float* __restrict__ in,
                                                   u16* __restrict__ out, int n) {
  int i = (blockIdx.x * 256 + threadIdx.x) * 4;
  if (i >= n) return;
  float4 v = *(const float4*)(in + i);
  ushort4 o;
  o.x = f2bf(v.x); o.y = f2bf(v.y); o.z = f2bf(v.z); o.w = f2bf(v.w);
  *(ushort4*)(out + i) = o;
}

// ---------------- GEMM: C[m,n] = sum_k A[m,k]*Bt[n,k] + bias[n] ----------------
template<bool OUT_F32>
__global__ __launch_bounds__(256) void gemm_bt_k(
    const u16* __restrict__ A, const u16* __restrict__ Bt,
    const float* __restrict__ bias, void* __restrict__ Cout,
    int Ndim, int Kdim) {
  __shared__ __align__(16) u16 As[128][64];
  __shared__ __align__(16) u16 Bs[128][64];
  const int tid = threadIdx.x;
  const int lane = tid & 63, wid = tid >> 6;
  const int wr = wid >> 1, wc = wid & 1;
  const int l15 = lane & 15, lg = lane >> 4;
  const int bm = blockIdx.y * 128;
  const int bn = blockIdx.x * 128;

  f32x4 acc[4][4];
#pragma unroll
  for (int i = 0; i < 4; i++)
#pragma unroll
    for (int j = 0; j < 4; j++) acc[i][j] = f32x4{0.f, 0.f, 0.f, 0.f};

  for (int kt = 0; kt < Kdim; kt += 64) {
#pragma unroll
    for (int it = 0; it < 4; ++it) {
      int c = it * 256 + tid;
      int rr = c >> 3, cc = c & 7;
      gload_lds16(A + (size_t)(bm + rr) * Kdim + kt + cc * 8, (u16*)As + c * 8);
      gload_lds16(Bt + (size_t)(bn + rr) * Kdim + kt + cc * 8, (u16*)Bs + c * 8);
    }
    __syncthreads();
#pragma unroll
    for (int ks = 0; ks < 2; ++ks) {
      bf16x8 af[4], bfr[4];
#pragma unroll
      for (int i = 0; i < 4; i++)
        af[i] = *(const bf16x8*)&As[wr * 64 + i * 16 + l15][ks * 32 + lg * 8];
#pragma unroll
      for (int j = 0; j < 4; j++)
        bfr[j] = *(const bf16x8*)&Bs[wc * 64 + j * 16 + l15][ks * 32 + lg * 8];
#pragma unroll
      for (int i = 0; i < 4; i++)
#pragma unroll
        for (int j = 0; j < 4; j++)
          acc[i][j] = __builtin_amdgcn_mfma_f32_16x16x32_bf16(af[i], bfr[j], acc[i][j], 0, 0, 0);
    }
    __syncthreads();
  }
#pragma unroll
  for (int j = 0; j < 4; j++) {
    const int cj = bn + wc * 64 + j * 16 + l15;
    const float bv = bias[cj];
#pragma unroll
    for (int i = 0; i < 4; i++) {
      const int r0 = bm + wr * 64 + i * 16 + lg * 4;
#pragma unroll
      for (int r = 0; r < 4; r++) {
        float v = acc[i][j][r] + bv;
        if (OUT_F32) ((float*)Cout)[(size_t)(r0 + r) * Ndim + cj] = v;
        else         ((u16*)Cout)[(size_t)(r0 + r) * Ndim + cj] = f2bf(v);
      }
    }
  }
}

// ---------------- fused RMSNorm + RoPE (in-place on q,k; bf16 storage) ----------------
// Q additionally pre-scaled by SCALE_L2E so attention scores are directly in exp2 domain.
__global__ __launch_bounds__(256) void rmsrope_k(
    u16* __restrict__ qk, const float* __restrict__ gq, const float* __restrict__ gk,
    const float* __restrict__ freqs) {
  const int t = blockIdx.x;        // token
  const int s = t & (SEQ - 1);
  const int tid = threadIdx.x;
  __shared__ float red[8];

  for (int which = 0; which < 2; ++which) {
    u16* row = qk + (size_t)which * ((size_t)MTOK * DIMC) + (size_t)t * DIMC;
    const float* g = which ? gk : gq;
    const float oscale = which ? 1.0f : SCALE_L2E;
    uint4 raw = *(const uint4*)(row + tid * 8);
    const u16* rb = (const u16*)&raw;
    float v[8], ss = 0.f;
#pragma unroll
    for (int e = 0; e < 8; e++) { v[e] = bf2f(rb[e]); ss += v[e] * v[e]; }
#pragma unroll
    for (int m = 1; m < 64; m <<= 1) ss += __shfl_xor(ss, m);
    if ((tid & 63) == 0) red[which * 4 + (tid >> 6)] = ss;
    __syncthreads();
    float tot = red[which * 4] + red[which * 4 + 1] + red[which * 4 + 2] + red[which * 4 + 3];
    float rms = rsqrtf(tot * (1.0f / (float)DIMC) + 1e-6f);
    const int ch0 = tid * 8;
    const int d0 = ch0 & (HD - 1);
    u16 ob[8];
#pragma unroll
    for (int p = 0; p < 4; p++) {
      float fr = freqs[s * (HD / 2) + (d0 >> 1) + p];
      float cs = cosf(fr), sn = sinf(fr);
      float e = v[2 * p] * rms * g[ch0 + 2 * p];
      float o = v[2 * p + 1] * rms * g[ch0 + 2 * p + 1];
      ob[2 * p]     = f2bf((e * cs - o * sn) * oscale);
      ob[2 * p + 1] = f2bf((e * sn + o * cs) * oscale);
    }
    *(uint4*)(row + tid * 8) = *(const uint4*)ob;
    __syncthreads();
  }
}

// ---------------- transpose V: v[t][c] -> vT[(b*2048+c)][s] ----------------
__global__ __launch_bounds__(256) void vtrans_k(const u16* __restrict__ v, u16* __restrict__ vT) {
  __shared__ u16 tile[64][72];
  const int s0 = blockIdx.x * 64, c0 = blockIdx.y * 64, b = blockIdx.z;
  const int tid = threadIdx.x;
  const int rr = tid >> 3, cc8 = (tid & 7) * 8;
#pragma unroll
  for (int it = 0; it < 2; ++it) {
    int si = it * 32 + rr;
    uint4 d = *(const uint4*)(v + ((size_t)(b * SEQ + s0 + si)) * DIMC + c0 + cc8);
    const u16* dp = (const u16*)&d;
#pragma unroll
    for (int e = 0; e < 8; e++) tile[si][cc8 + e] = dp[e];
  }
  __syncthreads();
#pragma unroll
  for (int it = 0; it < 2; ++it) {
    int ci = it * 32 + rr;
    u16 buf[8];
#pragma unroll
    for (int e = 0; e < 8; e++) buf[e] = tile[cc8 + e][ci];
    *(uint4*)(vT + ((size_t)(b * DIMC + c0 + ci)) * SEQ + s0 + cc8) = *(const uint4*)buf;
  }
}

// ---------------- flash attention ----------------
// grid: (SEQ/128, B*NH). 4 waves x 32 q-rows (2 rowsets of 16). KV tile 64,
// double-buffered K/V (distinct shared arrays -> loads stay ahead of compute),
// one barrier per tile. Defer-max online softmax (THR=8, exp2 domain).
#define PSWZ(q) ((((q) & 7) << 3) ^ (((q) & 8) << 1))

#define STAGE_TILE(KS, VS, kv0)                                                \
  _Pragma("unroll") for (int it = 0; it < 4; ++it) {                           \
    const int c = it * 256 + tid;                                              \
    { const int rr = c >> 4, cc = c & 15;                                      \
      gload_lds16(Kp + (size_t)((kv0) + rr) * DIMC + ((cc ^ (rr & 7)) * 8),    \
                  (u16*)(KS) + c * 8); }                                       \
    { const int rr = c >> 3, cc = c & 7;                                       \
      gload_lds16(Vp + (size_t)rr * SEQ + (kv0) + ((cc ^ (rr & 7)) * 8),       \
                  (u16*)(VS) + c * 8); }                                       \
  }

#define COMPUTE_TILE(KS, VS)                                                   \
  {                                                                            \
    f32x4 sc[2][4];                                                            \
    _Pragma("unroll") for (int kj = 0; kj < 4; kj++) {                         \
      sc[0][kj] = f32x4{0.f, 0.f, 0.f, 0.f};                                   \
      sc[1][kj] = f32x4{0.f, 0.f, 0.f, 0.f};                                   \
    }                                                                          \
    _Pragma("unroll") for (int kj = 0; kj < 4; kj++) {                         \
      const int row = kj * 16 + l15;                                           \
      _Pragma("unroll") for (int ks = 0; ks < 4; ks++) {                       \
        const bf16x8 bfr = *(const bf16x8*)((const char*)(KS) + row * 256 +    \
                           ((ks * 64 + lg * 16) ^ ((row & 7) << 4)));          \
        sc[0][kj] = __builtin_amdgcn_mfma_f32_16x16x32_bf16(qf[0][ks], bfr, sc[0][kj], 0, 0, 0); \
        sc[1][kj] = __builtin_amdgcn_mfma_f32_16x16x32_bf16(qf[1][ks], bfr, sc[1][kj], 0, 0, 0); \
      }                                                                        \
    }                                                                          \
    _Pragma("unroll") for (int rs = 0; rs < 2; rs++) {                         \
      float rmax[4];                                                           \
      _Pragma("unroll") for (int r = 0; r < 4; r++)                            \
        rmax[r] = fmaxf(fmaxf(sc[rs][0][r], sc[rs][1][r]),                     \
                        fmaxf(sc[rs][2][r], sc[rs][3][r]));                    \
      _Pragma("unroll") for (int m = 1; m < 16; m <<= 1)                       \
        _Pragma("unroll") for (int r = 0; r < 4; r++)                          \
          rmax[r] = fmaxf(rmax[r], __shfl_xor(rmax[r], m));                    \
      bool okd = true;                                                         \
      _Pragma("unroll") for (int r = 0; r < 4; r++)                            \
        okd = okd && (rmax[r] - mcur[rs][r] <= 8.0f);                          \
      if (!__all(okd)) {                                                       \
        _Pragma("unroll") for (int r = 0; r < 4; r++) {                        \
          float mn = fmaxf(mcur[rs][r], rmax[r]);                              \
          float al = exp2f(mcur[rs][r] - mn);                                  \
          mcur[rs][r] = mn;                                                    \
          lcur[rs][r] *= al;                                                   \
          _Pragma("unroll") for (int dj = 0; dj < 8; dj++)                     \
            accO[rs][dj][r] *= al;                                             \
        }                                                                      \
      }                                                                        \
      float rsum[4] = {0.f, 0.f, 0.f, 0.f};                                    \
      _Pragma("unroll") for (int kj = 0; kj < 4; kj++) {                       \
        _Pragma("unroll") for (int r = 0; r < 4; r++) {                        \
          float p = exp2f(sc[rs][kj][r] - mcur[rs][r]);                        \
          rsum[r] += p;                                                        \
          const int qr = lg * 4 + r;                                           \
          Ps[wid][rs][qr * 64 + ((kj * 16 + l15) ^ PSWZ(qr))] = f2bf(p);       \
        }                                                                      \
      }                                                                        \
      _Pragma("unroll") for (int m = 1; m < 16; m <<= 1)                       \
        _Pragma("unroll") for (int r = 0; r < 4; r++)                          \
          rsum[r] += __shfl_xor(rsum[r], m);                                   \
      _Pragma("unroll") for (int r = 0; r < 4; r++) lcur[rs][r] += rsum[r];    \
    }                                                                          \
    _Pragma("unroll") for (int ks2 = 0; ks2 < 2; ks2++) {                      \
      const bf16x8 pa0 = *(const bf16x8*)((const char*)&Ps[wid][0][0] +        \
          l15 * 128 + 2 * ((ks2 * 32 + lg * 8) ^ PSWZ(l15)));                  \
      const bf16x8 pa1 = *(const bf16x8*)((const char*)&Ps[wid][1][0] +        \
          l15 * 128 + 2 * ((ks2 * 32 + lg * 8) ^ PSWZ(l15)));                  \
      _Pragma("unroll") for (int dj = 0; dj < 8; dj++) {                       \
        const int vrow = dj * 16 + l15;                                        \
        const bf16x8 vb = *(const bf16x8*)((const char*)(VS) + vrow * 128 +    \
                          ((ks2 * 64 + lg * 16) ^ ((vrow & 7) << 4)));         \
        accO[0][dj] = __builtin_amdgcn_mfma_f32_16x16x32_bf16(pa0, vb, accO[0][dj], 0, 0, 0); \
        accO[1][dj] = __builtin_amdgcn_mfma_f32_16x16x32_bf16(pa1, vb, accO[1][dj], 0, 0, 0); \
      }                                                                        \
    }                                                                          \
  }

__global__ __launch_bounds__(256, 2) void attn_k(
    const u16* __restrict__ qbuf, const u16* __restrict__ kbuf,
    const u16* __restrict__ vT, u16* __restrict__ obuf) {
  const int bh = blockIdx.y, b = bh >> 4, h = bh & 15;
  const int q0 = blockIdx.x * 128;
  const int tid = threadIdx.x, lane = tid & 63, wid = tid >> 6;
  const int l15 = lane & 15, lg = lane >> 4;

  __shared__ __align__(16) u16 Ks0[64 * 128];
  __shared__ __align__(16) u16 Vs0[128 * 64];
  __shared__ __align__(16) u16 Ks1[64 * 128];
  __shared__ __align__(16) u16 Vs1[128 * 64];
  __shared__ __align__(16) u16 Ps[4][2][16 * 64];

  const size_t qkbase = (size_t)(b * SEQ) * DIMC + h * HD;
  const u16* Qp = qbuf + qkbase;
  const u16* Kp = kbuf + qkbase;
  const u16* Vp = vT + (size_t)(b * DIMC + h * HD) * SEQ;

  bf16x8 qf[2][4];
#pragma unroll
  for (int rs = 0; rs < 2; rs++) {
    const int qrow = q0 + wid * 32 + rs * 16 + l15;
#pragma unroll
    for (int ks = 0; ks < 4; ++ks)
      qf[rs][ks] = *(const bf16x8*)(Qp + (size_t)qrow * DIMC + ks * 32 + lg * 8);
  }

  float mcur[2][4], lcur[2][4];
#pragma unroll
  for (int rs = 0; rs < 2; rs++)
#pragma unroll
    for (int r = 0; r < 4; r++) { mcur[rs][r] = -1e30f; lcur[rs][r] = 0.f; }
  f32x4 accO[2][8];
#pragma unroll
  for (int rs = 0; rs < 2; rs++)
#pragma unroll
    for (int dj = 0; dj < 8; dj++) accO[rs][dj] = f32x4{0.f, 0.f, 0.f, 0.f};

  STAGE_TILE(Ks0, Vs0, 0);
  __syncthreads();

#pragma unroll 1
  for (int t = 0; t < SEQ / 64; t += 2) {
    STAGE_TILE(Ks1, Vs1, (t + 1) * 64);
    COMPUTE_TILE(Ks0, Vs0);
    __syncthreads();
    if (t + 2 < SEQ / 64) STAGE_TILE(Ks0, Vs0, (t + 2) * 64);
    COMPUTE_TILE(Ks1, Vs1);
    __syncthreads();
  }

  u16* Op = obuf + (size_t)(b * SEQ + q0 + wid * 32) * DIMC + h * HD;
#pragma unroll
  for (int rs = 0; rs < 2; rs++) {
    float linv[4];
#pragma unroll
    for (int r = 0; r < 4; r++) linv[r] = 1.0f / lcur[rs][r];
#pragma unroll
    for (int dj = 0; dj < 8; dj++)
#pragma unroll
      for (int r = 0; r < 4; r++) {
        int rq = rs * 16 + lg * 4 + r;
        Op[(size_t)rq * DIMC + dj * 16 + l15] = f2bf(accO[rs][dj][r] * linv[r]);
      }
  }
}

// ---------------- launch ----------------
extern "C" void kernel_launch(void* const* d_in, const int* in_sizes, int n_in,
                              void* d_out, int out_size, void* d_ws, size_t ws_size,
                              hipStream_t stream) {
  const float* x     = (const float*)d_in[0];
  const float* freqs = (const float*)d_in[2];
  const float* wq = (const float*)d_in[3];
  const float* bq = (const float*)d_in[4];
  const float* wk = (const float*)d_in[5];
  const float* bk = (const float*)d_in[6];
  const float* wv = (const float*)d_in[7];
  const float* bv = (const float*)d_in[8];
  const float* wo = (const float*)d_in[9];
  const float* bo = (const float*)d_in[10];
  const float* gq = (const float*)d_in[11];
  const float* gk = (const float*)d_in[12];

  const size_t WS = (size_t)DIMC * DIMC;       // weight elems
  const size_t QS = (size_t)MTOK * DIMC;       // activation elems
  char* ws = (char*)d_ws;
  u16* xb  = (u16*)ws;  ws += QS * 2;
  u16* wb  = (u16*)ws;  ws += 4 * WS * 2;
  u16* qkv = (u16*)ws;  ws += 3 * QS * 2;
  u16* vT  = (u16*)ws;  ws += QS * 2;
  u16* ob  = (u16*)ws;  ws += QS * 2;

  cast_bf16_k<<<(int)(QS / 1024), 256, 0, stream>>>(x, xb, (int)QS);
  cast_bf16_k<<<(int)(WS / 1024), 256, 0, stream>>>(wq, wb + 0 * WS, (int)WS);
  cast_bf16_k<<<(int)(WS / 1024), 256, 0, stream>>>(wk, wb + 1 * WS, (int)WS);
  cast_bf16_k<<<(int)(WS / 1024), 256, 0, stream>>>(wv, wb + 2 * WS, (int)WS);
  cast_bf16_k<<<(int)(WS / 1024), 256, 0, stream>>>(wo, wb + 3 * WS, (int)WS);

  dim3 ggrid(DIMC / 128, MTOK / 128);
  gemm_bt_k<false><<<ggrid, 256, 0, stream>>>(xb, wb + 0 * WS, bq, qkv + 0 * QS, DIMC, DIMC);
  gemm_bt_k<false><<<ggrid, 256, 0, stream>>>(xb, wb + 1 * WS, bk, qkv + 1 * QS, DIMC, DIMC);
  gemm_bt_k<false><<<ggrid, 256, 0, stream>>>(xb, wb + 2 * WS, bv, qkv + 2 * QS, DIMC, DIMC);

  rmsrope_k<<<MTOK, 256, 0, stream>>>(qkv, gq, gk, freqs);
  vtrans_k<<<dim3(SEQ / 64, DIMC / 64, BSZ), 256, 0, stream>>>(qkv + 2 * QS, vT);
  attn_k<<<dim3(SEQ / 128, BSZ * NH), 256, 0, stream>>>(qkv, qkv + 1 * QS, vT, ob);

  gemm_bt_k<true><<<ggrid, 256, 0, stream>>>(ob, wb + 3 * WS, bo, d_out, DIMC, DIMC);
}

// Round 3
// 922.523 us; speedup vs baseline: 1.6797x; 1.1187x over previous
//
#include <hip/hip_runtime.h>
#include <hip/hip_bf16.h>

typedef unsigned short u16;
typedef __bf16 bf16x8 __attribute__((ext_vector_type(8)));
typedef float f32x4 __attribute__((ext_vector_type(4)));

#define DIMC  2048
#define NH    16
#define HD    128
#define BSZ   2
#define SEQ   4096
#define MTOK  (BSZ*SEQ)   /* 8192 tokens */

// scale * log2(e): folded into Q at rmsrope time
#define SCALE_L2E (0.08838834764831845f * 1.4426950408889634f)

__device__ __forceinline__ u16 f2bf(float f) {
  unsigned u = __float_as_uint(f);
  u += 0x7fff + ((u >> 16) & 1);   // RTNE
  return (u16)(u >> 16);
}
__device__ __forceinline__ float bf2f(u16 b) {
  return __uint_as_float(((unsigned)b) << 16);
}

__device__ __forceinline__ void gload_lds16(const void* g, void* l) {
  __builtin_amdgcn_global_load_lds(
      (const __attribute__((address_space(1))) void*)g,
      (__attribute__((address_space(3))) void*)l, 16, 0, 0);
}

// 16-lane (DPP-row) butterfly reductions on the VALU pipe — no DS ops.
// xor1 = quad_perm(1,0,3,2)=0xB1; xor2 = quad_perm(2,3,0,1)=0x4E;
// l^7 = row_half_mirror=0x141; l^15 = row_mirror=0x140.
template<int CTRL>
__device__ __forceinline__ float dppf(float x) {
  return __int_as_float(__builtin_amdgcn_mov_dpp(__float_as_int(x), CTRL, 0xf, 0xf, true));
}
__device__ __forceinline__ float rmax16(float x) {
  x = fmaxf(x, dppf<0xB1>(x));
  x = fmaxf(x, dppf<0x4E>(x));
  x = fmaxf(x, dppf<0x141>(x));
  x = fmaxf(x, dppf<0x140>(x));
  return x;
}
__device__ __forceinline__ float rsum16(float x) {
  x += dppf<0xB1>(x);
  x += dppf<0x4E>(x);
  x += dppf<0x141>(x);
  x += dppf<0x140>(x);
  return x;
}

// ---------------- cast f32 -> bf16 ----------------
__global__ __launch_bounds__(256) void cast_bf16_k(const float* __restrict__ in,
                                                   u16* __restrict__ out, int n) {
  int i = (blockIdx.x * 256 + threadIdx.x) * 4;
  if (i >= n) return;
  float4 v = *(const float4*)(in + i);
  ushort4 o;
  o.x = f2bf(v.x); o.y = f2bf(v.y); o.z = f2bf(v.z); o.w = f2bf(v.w);
  *(ushort4*)(out + i) = o;
}

// ---------------- GEMM: C[m,n] = sum_k A[m,k]*Bt[n,k] + bias[n] ----------------
// 128x128 tile, BK=64, 4 waves. XCD-aware block swizzle (grid = 1024 = 8*128).
template<bool OUT_F32>
__global__ __launch_bounds__(256) void gemm_bt_k(
    const u16* __restrict__ A, const u16* __restrict__ Bt,
    const float* __restrict__ bias, void* __restrict__ Cout,
    int Ndim, int Kdim) {
  __shared__ __align__(16) u16 As[128][64];
  __shared__ __align__(16) u16 Bs[128][64];
  const int tid = threadIdx.x;
  const int lane = tid & 63, wid = tid >> 6;
  const int wr = wid >> 1, wc = wid & 1;
  const int l15 = lane & 15, lg = lane >> 4;

  const int flat = blockIdx.y * gridDim.x + blockIdx.x;
  const int cpx = (gridDim.x * gridDim.y) >> 3;
  const int swz = (flat & 7) * cpx + (flat >> 3);
  const int bm = (swz / gridDim.x) * 128;
  const int bn = (swz % gridDim.x) * 128;

  f32x4 acc[4][4];
#pragma unroll
  for (int i = 0; i < 4; i++)
#pragma unroll
    for (int j = 0; j < 4; j++) acc[i][j] = f32x4{0.f, 0.f, 0.f, 0.f};

  for (int kt = 0; kt < Kdim; kt += 64) {
#pragma unroll
    for (int it = 0; it < 4; ++it) {
      int c = it * 256 + tid;
      int rr = c >> 3, cc = c & 7;
      gload_lds16(A + (size_t)(bm + rr) * Kdim + kt + cc * 8, (u16*)As + c * 8);
      gload_lds16(Bt + (size_t)(bn + rr) * Kdim + kt + cc * 8, (u16*)Bs + c * 8);
    }
    __syncthreads();
#pragma unroll
    for (int ks = 0; ks < 2; ++ks) {
      bf16x8 af[4], bfr[4];
#pragma unroll
      for (int i = 0; i < 4; i++)
        af[i] = *(const bf16x8*)&As[wr * 64 + i * 16 + l15][ks * 32 + lg * 8];
#pragma unroll
      for (int j = 0; j < 4; j++)
        bfr[j] = *(const bf16x8*)&Bs[wc * 64 + j * 16 + l15][ks * 32 + lg * 8];
#pragma unroll
      for (int i = 0; i < 4; i++)
#pragma unroll
        for (int j = 0; j < 4; j++)
          acc[i][j] = __builtin_amdgcn_mfma_f32_16x16x32_bf16(af[i], bfr[j], acc[i][j], 0, 0, 0);
    }
    __syncthreads();
  }
#pragma unroll
  for (int j = 0; j < 4; j++) {
    const int cj = bn + wc * 64 + j * 16 + l15;
    const float bv = bias[cj];
#pragma unroll
    for (int i = 0; i < 4; i++) {
      const int r0 = bm + wr * 64 + i * 16 + lg * 4;
#pragma unroll
      for (int r = 0; r < 4; r++) {
        float v = acc[i][j][r] + bv;
        if (OUT_F32) ((float*)Cout)[(size_t)(r0 + r) * Ndim + cj] = v;
        else         ((u16*)Cout)[(size_t)(r0 + r) * Ndim + cj] = f2bf(v);
      }
    }
  }
}

// ---------------- fused RMSNorm + RoPE (in-place on q,k; bf16 storage) ----------------
__global__ __launch_bounds__(256) void rmsrope_k(
    u16* __restrict__ qk, const float* __restrict__ gq, const float* __restrict__ gk,
    const float* __restrict__ freqs) {
  const int t = blockIdx.x;        // token
  const int s = t & (SEQ - 1);
  const int tid = threadIdx.x;
  __shared__ float red[8];

  for (int which = 0; which < 2; ++which) {
    u16* row = qk + (size_t)which * ((size_t)MTOK * DIMC) + (size_t)t * DIMC;
    const float* g = which ? gk : gq;
    const float oscale = which ? 1.0f : SCALE_L2E;
    uint4 raw = *(const uint4*)(row + tid * 8);
    const u16* rb = (const u16*)&raw;
    float v[8], ss = 0.f;
#pragma unroll
    for (int e = 0; e < 8; e++) { v[e] = bf2f(rb[e]); ss += v[e] * v[e]; }
#pragma unroll
    for (int m = 1; m < 64; m <<= 1) ss += __shfl_xor(ss, m);
    if ((tid & 63) == 0) red[which * 4 + (tid >> 6)] = ss;
    __syncthreads();
    float tot = red[which * 4] + red[which * 4 + 1] + red[which * 4 + 2] + red[which * 4 + 3];
    float rms = rsqrtf(tot * (1.0f / (float)DIMC) + 1e-6f);
    const int ch0 = tid * 8;
    const int d0 = ch0 & (HD - 1);
    u16 ob[8];
#pragma unroll
    for (int p = 0; p < 4; p++) {
      float fr = freqs[s * (HD / 2) + (d0 >> 1) + p];
      float cs = cosf(fr), sn = sinf(fr);
      float e = v[2 * p] * rms * g[ch0 + 2 * p];
      float o = v[2 * p + 1] * rms * g[ch0 + 2 * p + 1];
      ob[2 * p]     = f2bf((e * cs - o * sn) * oscale);
      ob[2 * p + 1] = f2bf((e * sn + o * cs) * oscale);
    }
    *(uint4*)(row + tid * 8) = *(const uint4*)ob;
    __syncthreads();
  }
}

// ---------------- transpose V: v[t][c] -> vT[(b*2048+c)][s] ----------------
__global__ __launch_bounds__(256) void vtrans_k(const u16* __restrict__ v, u16* __restrict__ vT) {
  __shared__ u16 tile[64][72];
  const int s0 = blockIdx.x * 64, c0 = blockIdx.y * 64, b = blockIdx.z;
  const int tid = threadIdx.x;
  const int rr = tid >> 3, cc8 = (tid & 7) * 8;
#pragma unroll
  for (int it = 0; it < 2; ++it) {
    int si = it * 32 + rr;
    uint4 d = *(const uint4*)(v + ((size_t)(b * SEQ + s0 + si)) * DIMC + c0 + cc8);
    const u16* dp = (const u16*)&d;
#pragma unroll
    for (int e = 0; e < 8; e++) tile[si][cc8 + e] = dp[e];
  }
  __syncthreads();
#pragma unroll
  for (int it = 0; it < 2; ++it) {
    int ci = it * 32 + rr;
    u16 buf[8];
#pragma unroll
    for (int e = 0; e < 8; e++) buf[e] = tile[cc8 + e][ci];
    *(uint4*)(vT + ((size_t)(b * DIMC + c0 + ci)) * SEQ + s0 + cc8) = *(const uint4*)buf;
  }
}

// ---------------- flash attention ----------------
// grid: 1024 blocks (SEQ/128 x B*NH), XCD-swizzled. 4 waves x 32 q-rows.
// KV tile 64, double-buffered K/V. Softmax reductions on VALU via DPP.
#define PSWZ(q) ((((q) & 7) << 3) ^ (((q) & 8) << 1))

#define STAGE_TILE(KS, VS, kv0)                                                \
  _Pragma("unroll") for (int it = 0; it < 4; ++it) {                           \
    const int c = it * 256 + tid;                                              \
    { const int rr = c >> 4, cc = c & 15;                                      \
      gload_lds16(Kp + (size_t)((kv0) + rr) * DIMC + ((cc ^ (rr & 7)) * 8),    \
                  (u16*)(KS) + c * 8); }                                       \
    { const int rr = c >> 3, cc = c & 7;                                       \
      gload_lds16(Vp + (size_t)rr * SEQ + (kv0) + ((cc ^ (rr & 7)) * 8),       \
                  (u16*)(VS) + c * 8); }                                       \
  }

#define COMPUTE_TILE(KS, VS)                                                   \
  {                                                                            \
    f32x4 sc[2][4];                                                            \
    _Pragma("unroll") for (int kj = 0; kj < 4; kj++) {                         \
      sc[0][kj] = f32x4{0.f, 0.f, 0.f, 0.f};                                   \
      sc[1][kj] = f32x4{0.f, 0.f, 0.f, 0.f};                                   \
    }                                                                          \
    _Pragma("unroll") for (int kj = 0; kj < 4; kj++) {                         \
      const int row = kj * 16 + l15;                                           \
      _Pragma("unroll") for (int ks = 0; ks < 4; ks++) {                       \
        const bf16x8 bfr = *(const bf16x8*)((const char*)(KS) + row * 256 +    \
                           ((ks * 64 + lg * 16) ^ ((row & 7) << 4)));          \
        sc[0][kj] = __builtin_amdgcn_mfma_f32_16x16x32_bf16(qf[0][ks], bfr, sc[0][kj], 0, 0, 0); \
        sc[1][kj] = __builtin_amdgcn_mfma_f32_16x16x32_bf16(qf[1][ks], bfr, sc[1][kj], 0, 0, 0); \
      }                                                                        \
    }                                                                          \
    _Pragma("unroll") for (int rs = 0; rs < 2; rs++) {                         \
      float rmax[4];                                                           \
      _Pragma("unroll") for (int r = 0; r < 4; r++)                            \
        rmax[r] = rmax16(fmaxf(fmaxf(sc[rs][0][r], sc[rs][1][r]),              \
                               fmaxf(sc[rs][2][r], sc[rs][3][r])));            \
      bool okd = true;                                                         \
      _Pragma("unroll") for (int r = 0; r < 4; r++)                            \
        okd = okd && (rmax[r] - mcur[rs][r] <= 8.0f);                          \
      if (!__all(okd)) {                                                       \
        _Pragma("unroll") for (int r = 0; r < 4; r++) {                        \
          float mn = fmaxf(mcur[rs][r], rmax[r]);                              \
          float al = exp2f(mcur[rs][r] - mn);                                  \
          mcur[rs][r] = mn;                                                    \
          lcur[rs][r] *= al;                                                   \
          _Pragma("unroll") for (int dj = 0; dj < 8; dj++)                     \
            accO[rs][dj][r] *= al;                                             \
        }                                                                      \
      }                                                                        \
      _Pragma("unroll") for (int r = 0; r < 4; r++) {                          \
        const float p0 = exp2f(sc[rs][0][r] - mcur[rs][r]);                    \
        const float p1 = exp2f(sc[rs][1][r] - mcur[rs][r]);                    \
        const float p2 = exp2f(sc[rs][2][r] - mcur[rs][r]);                    \
        const float p3 = exp2f(sc[rs][3][r] - mcur[rs][r]);                    \
        unsigned pkA, pkB;                                                     \
        asm("v_cvt_pk_bf16_f32 %0, %1, %2" : "=v"(pkA) : "v"(p0), "v"(p1));    \
        asm("v_cvt_pk_bf16_f32 %0, %1, %2" : "=v"(pkB) : "v"(p2), "v"(p3));    \
        const int qr = lg * 4 + r;                                             \
        u16* pb = &Ps[wid][rs][qr * 64];                                       \
        pb[(0 * 16 + l15) ^ PSWZ(qr)] = (u16)pkA;                              \
        pb[(1 * 16 + l15) ^ PSWZ(qr)] = (u16)(pkA >> 16);                      \
        pb[(2 * 16 + l15) ^ PSWZ(qr)] = (u16)pkB;                              \
        pb[(3 * 16 + l15) ^ PSWZ(qr)] = (u16)(pkB >> 16);                      \
        lcur[rs][r] += rsum16((p0 + p1) + (p2 + p3));                          \
      }                                                                        \
    }                                                                          \
    _Pragma("unroll") for (int ks2 = 0; ks2 < 2; ks2++) {                      \
      const bf16x8 pa0 = *(const bf16x8*)((const char*)&Ps[wid][0][0] +        \
          l15 * 128 + 2 * ((ks2 * 32 + lg * 8) ^ PSWZ(l15)));                  \
      const bf16x8 pa1 = *(const bf16x8*)((const char*)&Ps[wid][1][0] +        \
          l15 * 128 + 2 * ((ks2 * 32 + lg * 8) ^ PSWZ(l15)));                  \
      _Pragma("unroll") for (int dj = 0; dj < 8; dj++) {                       \
        const int vrow = dj * 16 + l15;                                        \
        const bf16x8 vb = *(const bf16x8*)((const char*)(VS) + vrow * 128 +    \
                          ((ks2 * 64 + lg * 16) ^ ((vrow & 7) << 4)));         \
        accO[0][dj] = __builtin_amdgcn_mfma_f32_16x16x32_bf16(pa0, vb, accO[0][dj], 0, 0, 0); \
        accO[1][dj] = __builtin_amdgcn_mfma_f32_16x16x32_bf16(pa1, vb, accO[1][dj], 0, 0, 0); \
      }                                                                        \
    }                                                                          \
  }

__global__ __launch_bounds__(256, 2) void attn_k(
    const u16* __restrict__ qbuf, const u16* __restrict__ kbuf,
    const u16* __restrict__ vT, u16* __restrict__ obuf) {
  const int flat = blockIdx.y * gridDim.x + blockIdx.x;   // 1024 total
  const int swz = (flat & 7) * 128 + (flat >> 3);         // XCD chunks of 128
  const int bh = swz >> 5, b = bh >> 4, h = bh & 15;
  const int q0 = (swz & 31) * 128;
  const int tid = threadIdx.x, lane = tid & 63, wid = tid >> 6;
  const int l15 = lane & 15, lg = lane >> 4;

  __shared__ __align__(16) u16 Ks0[64 * 128];
  __shared__ __align__(16) u16 Vs0[128 * 64];
  __shared__ __align__(16) u16 Ks1[64 * 128];
  __shared__ __align__(16) u16 Vs1[128 * 64];
  __shared__ __align__(16) u16 Ps[4][2][16 * 64];

  const size_t qkbase = (size_t)(b * SEQ) * DIMC + h * HD;
  const u16* Qp = qbuf + qkbase;
  const u16* Kp = kbuf + qkbase;
  const u16* Vp = vT + (size_t)(b * DIMC + h * HD) * SEQ;

  bf16x8 qf[2][4];
#pragma unroll
  for (int rs = 0; rs < 2; rs++) {
    const int qrow = q0 + wid * 32 + rs * 16 + l15;
#pragma unroll
    for (int ks = 0; ks < 4; ++ks)
      qf[rs][ks] = *(const bf16x8*)(Qp + (size_t)qrow * DIMC + ks * 32 + lg * 8);
  }

  float mcur[2][4], lcur[2][4];
#pragma unroll
  for (int rs = 0; rs < 2; rs++)
#pragma unroll
    for (int r = 0; r < 4; r++) { mcur[rs][r] = -1e30f; lcur[rs][r] = 0.f; }
  f32x4 accO[2][8];
#pragma unroll
  for (int rs = 0; rs < 2; rs++)
#pragma unroll
    for (int dj = 0; dj < 8; dj++) accO[rs][dj] = f32x4{0.f, 0.f, 0.f, 0.f};

  STAGE_TILE(Ks0, Vs0, 0);
  __syncthreads();

#pragma unroll 1
  for (int t = 0; t < SEQ / 64; t += 2) {
    STAGE_TILE(Ks1, Vs1, (t + 1) * 64);
    COMPUTE_TILE(Ks0, Vs0);
    __syncthreads();
    if (t + 2 < SEQ / 64) STAGE_TILE(Ks0, Vs0, (t + 2) * 64);
    COMPUTE_TILE(Ks1, Vs1);
    __syncthreads();
  }

  u16* Op = obuf + (size_t)(b * SEQ + q0 + wid * 32) * DIMC + h * HD;
#pragma unroll
  for (int rs = 0; rs < 2; rs++) {
    float linv[4];
#pragma unroll
    for (int r = 0; r < 4; r++) linv[r] = 1.0f / lcur[rs][r];
#pragma unroll
    for (int dj = 0; dj < 8; dj++)
#pragma unroll
      for (int r = 0; r < 4; r++) {
        int rq = rs * 16 + lg * 4 + r;
        Op[(size_t)rq * DIMC + dj * 16 + l15] = f2bf(accO[rs][dj][r] * linv[r]);
      }
  }
}

// ---------------- launch ----------------
extern "C" void kernel_launch(void* const* d_in, const int* in_sizes, int n_in,
                              void* d_out, int out_size, void* d_ws, size_t ws_size,
                              hipStream_t stream) {
  const float* x     = (const float*)d_in[0];
  const float* freqs = (const float*)d_in[2];
  const float* wq = (const float*)d_in[3];
  const float* bq = (const float*)d_in[4];
  const float* wk = (const float*)d_in[5];
  const float* bk = (const float*)d_in[6];
  const float* wv = (const float*)d_in[7];
  const float* bv = (const float*)d_in[8];
  const float* wo = (const float*)d_in[9];
  const float* bo = (const float*)d_in[10];
  const float* gq = (const float*)d_in[11];
  const float* gk = (const float*)d_in[12];

  const size_t WS = (size_t)DIMC * DIMC;       // weight elems
  const size_t QS = (size_t)MTOK * DIMC;       // activation elems
  char* ws = (char*)d_ws;
  u16* xb  = (u16*)ws;  ws += QS * 2;
  u16* wb  = (u16*)ws;  ws += 4 * WS * 2;
  u16* qkv = (u16*)ws;  ws += 3 * QS * 2;
  u16* vT  = (u16*)ws;  ws += QS * 2;
  u16* ob  = (u16*)ws;  ws += QS * 2;

  cast_bf16_k<<<(int)(QS / 1024), 256, 0, stream>>>(x, xb, (int)QS);
  cast_bf16_k<<<(int)(WS / 1024), 256, 0, stream>>>(wq, wb + 0 * WS, (int)WS);
  cast_bf16_k<<<(int)(WS / 1024), 256, 0, stream>>>(wk, wb + 1 * WS, (int)WS);
  cast_bf16_k<<<(int)(WS / 1024), 256, 0, stream>>>(wv, wb + 2 * WS, (int)WS);
  cast_bf16_k<<<(int)(WS / 1024), 256, 0, stream>>>(wo, wb + 3 * WS, (int)WS);

  dim3 ggrid(DIMC / 128, MTOK / 128);
  gemm_bt_k<false><<<ggrid, 256, 0, stream>>>(xb, wb + 0 * WS, bq, qkv + 0 * QS, DIMC, DIMC);
  gemm_bt_k<false><<<ggrid, 256, 0, stream>>>(xb, wb + 1 * WS, bk, qkv + 1 * QS, DIMC, DIMC);
  gemm_bt_k<false><<<ggrid, 256, 0, stream>>>(xb, wb + 2 * WS, bv, qkv + 2 * QS, DIMC, DIMC);

  rmsrope_k<<<MTOK, 256, 0, stream>>>(qkv, gq, gk, freqs);
  vtrans_k<<<dim3(SEQ / 64, DIMC / 64, BSZ), 256, 0, stream>>>(qkv + 2 * QS, vT);
  attn_k<<<dim3(SEQ / 128, BSZ * NH), 256, 0, stream>>>(qkv, qkv + 1 * QS, vT, ob);

  gemm_bt_k<true><<<ggrid, 256, 0, stream>>>(ob, wb + 3 * WS, bo, d_out, DIMC, DIMC);
}

// Round 4
// 816.633 us; speedup vs baseline: 1.8975x; 1.1297x over previous
//
#include <hip/hip_runtime.h>
#include <hip/hip_bf16.h>

typedef unsigned short u16;
typedef __bf16 bf16x8 __attribute__((ext_vector_type(8)));
typedef float f32x4 __attribute__((ext_vector_type(4)));
typedef float f32x16 __attribute__((ext_vector_type(16)));

#define DIMC  2048
#define NH    16
#define HD    128
#define BSZ   2
#define SEQ   4096
#define MTOK  (BSZ*SEQ)   /* 8192 tokens */

// scale * log2(e): folded into Q at rmsrope time
#define SCALE_L2E (0.08838834764831845f * 1.4426950408889634f)

__device__ __forceinline__ u16 f2bf(float f) {
  unsigned u = __float_as_uint(f);
  u += 0x7fff + ((u >> 16) & 1);   // RTNE
  return (u16)(u >> 16);
}
__device__ __forceinline__ float bf2f(u16 b) {
  return __uint_as_float(((unsigned)b) << 16);
}

__device__ __forceinline__ void gload_lds16(const void* g, void* l) {
  __builtin_amdgcn_global_load_lds(
      (const __attribute__((address_space(1))) void*)g,
      (__attribute__((address_space(3))) void*)l, 16, 0, 0);
}

// ---------------- cast f32 -> bf16 ----------------
__global__ __launch_bounds__(256) void cast_bf16_k(const float* __restrict__ in,
                                                   u16* __restrict__ out, int n) {
  int i = (blockIdx.x * 256 + threadIdx.x) * 4;
  if (i >= n) return;
  float4 v = *(const float4*)(in + i);
  ushort4 o;
  o.x = f2bf(v.x); o.y = f2bf(v.y); o.z = f2bf(v.z); o.w = f2bf(v.w);
  *(ushort4*)(out + i) = o;
}

// ---------------- GEMM: C[m,n] = sum_k A[m,k]*Bt[n,k] + bias[n] ----------------
// 128x128 tile, BK=64, 4 waves. XCD-aware block swizzle (grid = 1024 = 8*128).
template<bool OUT_F32>
__global__ __launch_bounds__(256) void gemm_bt_k(
    const u16* __restrict__ A, const u16* __restrict__ Bt,
    const float* __restrict__ bias, void* __restrict__ Cout,
    int Ndim, int Kdim) {
  __shared__ __align__(16) u16 As[128][64];
  __shared__ __align__(16) u16 Bs[128][64];
  const int tid = threadIdx.x;
  const int lane = tid & 63, wid = tid >> 6;
  const int wr = wid >> 1, wc = wid & 1;
  const int l15 = lane & 15, lg = lane >> 4;

  const int flat = blockIdx.y * gridDim.x + blockIdx.x;
  const int cpx = (gridDim.x * gridDim.y) >> 3;
  const int swz = (flat & 7) * cpx + (flat >> 3);
  const int bm = (swz / gridDim.x) * 128;
  const int bn = (swz % gridDim.x) * 128;

  f32x4 acc[4][4];
#pragma unroll
  for (int i = 0; i < 4; i++)
#pragma unroll
    for (int j = 0; j < 4; j++) acc[i][j] = f32x4{0.f, 0.f, 0.f, 0.f};

  for (int kt = 0; kt < Kdim; kt += 64) {
#pragma unroll
    for (int it = 0; it < 4; ++it) {
      int c = it * 256 + tid;
      int rr = c >> 3, cc = c & 7;
      gload_lds16(A + (size_t)(bm + rr) * Kdim + kt + cc * 8, (u16*)As + c * 8);
      gload_lds16(Bt + (size_t)(bn + rr) * Kdim + kt + cc * 8, (u16*)Bs + c * 8);
    }
    __syncthreads();
#pragma unroll
    for (int ks = 0; ks < 2; ++ks) {
      bf16x8 af[4], bfr[4];
#pragma unroll
      for (int i = 0; i < 4; i++)
        af[i] = *(const bf16x8*)&As[wr * 64 + i * 16 + l15][ks * 32 + lg * 8];
#pragma unroll
      for (int j = 0; j < 4; j++)
        bfr[j] = *(const bf16x8*)&Bs[wc * 64 + j * 16 + l15][ks * 32 + lg * 8];
#pragma unroll
      for (int i = 0; i < 4; i++)
#pragma unroll
        for (int j = 0; j < 4; j++)
          acc[i][j] = __builtin_amdgcn_mfma_f32_16x16x32_bf16(af[i], bfr[j], acc[i][j], 0, 0, 0);
    }
    __syncthreads();
  }
#pragma unroll
  for (int j = 0; j < 4; j++) {
    const int cj = bn + wc * 64 + j * 16 + l15;
    const float bv = bias[cj];
#pragma unroll
    for (int i = 0; i < 4; i++) {
      const int r0 = bm + wr * 64 + i * 16 + lg * 4;
#pragma unroll
      for (int r = 0; r < 4; r++) {
        float v = acc[i][j][r] + bv;
        if (OUT_F32) ((float*)Cout)[(size_t)(r0 + r) * Ndim + cj] = v;
        else         ((u16*)Cout)[(size_t)(r0 + r) * Ndim + cj] = f2bf(v);
      }
    }
  }
}

// ---------------- fused RMSNorm + RoPE (in-place on q,k; bf16 storage) ----------------
__global__ __launch_bounds__(256) void rmsrope_k(
    u16* __restrict__ qk, const float* __restrict__ gq, const float* __restrict__ gk,
    const float* __restrict__ freqs) {
  const int t = blockIdx.x;        // token
  const int s = t & (SEQ - 1);
  const int tid = threadIdx.x;
  __shared__ float red[8];

  for (int which = 0; which < 2; ++which) {
    u16* row = qk + (size_t)which * ((size_t)MTOK * DIMC) + (size_t)t * DIMC;
    const float* g = which ? gk : gq;
    const float oscale = which ? 1.0f : SCALE_L2E;
    uint4 raw = *(const uint4*)(row + tid * 8);
    const u16* rb = (const u16*)&raw;
    float v[8], ss = 0.f;
#pragma unroll
    for (int e = 0; e < 8; e++) { v[e] = bf2f(rb[e]); ss += v[e] * v[e]; }
#pragma unroll
    for (int m = 1; m < 64; m <<= 1) ss += __shfl_xor(ss, m);
    if ((tid & 63) == 0) red[which * 4 + (tid >> 6)] = ss;
    __syncthreads();
    float tot = red[which * 4] + red[which * 4 + 1] + red[which * 4 + 2] + red[which * 4 + 3];
    float rms = rsqrtf(tot * (1.0f / (float)DIMC) + 1e-6f);
    const int ch0 = tid * 8;
    const int d0 = ch0 & (HD - 1);
    u16 ob[8];
#pragma unroll
    for (int p = 0; p < 4; p++) {
      float fr = freqs[s * (HD / 2) + (d0 >> 1) + p];
      float cs = cosf(fr), sn = sinf(fr);
      float e = v[2 * p] * rms * g[ch0 + 2 * p];
      float o = v[2 * p + 1] * rms * g[ch0 + 2 * p + 1];
      ob[2 * p]     = f2bf((e * cs - o * sn) * oscale);
      ob[2 * p + 1] = f2bf((e * sn + o * cs) * oscale);
    }
    *(uint4*)(row + tid * 8) = *(const uint4*)ob;
    __syncthreads();
  }
}

// ---------------- transpose V: v[t][c] -> vT[(b*2048+c)][s] ----------------
__global__ __launch_bounds__(256) void vtrans_k(const u16* __restrict__ v, u16* __restrict__ vT) {
  __shared__ u16 tile[64][72];
  const int s0 = blockIdx.x * 64, c0 = blockIdx.y * 64, b = blockIdx.z;
  const int tid = threadIdx.x;
  const int rr = tid >> 3, cc8 = (tid & 7) * 8;
#pragma unroll
  for (int it = 0; it < 2; ++it) {
    int si = it * 32 + rr;
    uint4 d = *(const uint4*)(v + ((size_t)(b * SEQ + s0 + si)) * DIMC + c0 + cc8);
    const u16* dp = (const u16*)&d;
#pragma unroll
    for (int e = 0; e < 8; e++) tile[si][cc8 + e] = dp[e];
  }
  __syncthreads();
#pragma unroll
  for (int it = 0; it < 2; ++it) {
    int ci = it * 32 + rr;
    u16 buf[8];
#pragma unroll
    for (int e = 0; e < 8; e++) buf[e] = tile[cc8 + e][ci];
    *(uint4*)(vT + ((size_t)(b * DIMC + c0 + ci)) * SEQ + s0 + cc8) = *(const uint4*)buf;
  }
}

// ---------------- flash attention: 32x32 swapped-QK^T, in-register softmax ----
// grid: 1024 blocks (SEQ/128 x B*NH), XCD-swizzled. 4 waves x 32 q-rows.
// S = mfma32(K, Q) -> S[k][q]: each lane owns a q-row slice in registers.
// P stays in registers: cvt_pk_bf16 + v_permlane32_swap -> PV A-fragments.
// K tile [64][128] swizzle: byte ^= (row&15)<<4 ; Vt tile [128][64]: byte ^= (row&7)<<4.

#define STAGE(KS, VS, kv0)                                                     \
  _Pragma("unroll") for (int it = 0; it < 4; ++it) {                           \
    const int c = it * 256 + tid;                                              \
    { const int rr = c >> 4, ss = c & 15;                                      \
      gload_lds16(Kp + (size_t)((kv0) + rr) * DIMC + ((ss ^ (rr & 15)) * 8),   \
                  (u16*)(KS) + c * 8); }                                       \
    { const int rr = c >> 3, ss = c & 7;                                       \
      gload_lds16(Vp + (size_t)rr * SEQ + (kv0) + ((ss ^ (rr & 7)) * 8),       \
                  (u16*)(VS) + c * 8); }                                       \
  }

#define CROW(r) (((r) & 3) + 8 * ((r) >> 2) + 4 * hi)

#define COMPUTE(KS, VS)                                                        \
  {                                                                            \
    f32x16 s0, s1;                                                             \
    _Pragma("unroll") for (int i = 0; i < 16; i++) { s0[i] = 0.f; s1[i] = 0.f; } \
    _Pragma("unroll") for (int j = 0; j < 8; ++j) {                            \
      const int byt = (j * 32 + hi * 16);                                      \
      const bf16x8 k0 = *(const bf16x8*)((const char*)(KS) + l31 * 256 +       \
                        (byt ^ ((l31 & 15) << 4)));                            \
      const bf16x8 k1 = *(const bf16x8*)((const char*)(KS) + (32 + l31) * 256 + \
                        (byt ^ ((l31 & 15) << 4)));                            \
      s0 = __builtin_amdgcn_mfma_f32_32x32x16_bf16(k0, qf[j], s0, 0, 0, 0);    \
      s1 = __builtin_amdgcn_mfma_f32_32x32x16_bf16(k1, qf[j], s1, 0, 0, 0);    \
    }                                                                          \
    float rmax = s0[0];                                                        \
    _Pragma("unroll") for (int r = 1; r < 16; r++) rmax = fmaxf(rmax, s0[r]);  \
    _Pragma("unroll") for (int r = 0; r < 16; r++) rmax = fmaxf(rmax, s1[r]);  \
    rmax = fmaxf(rmax, __shfl_xor(rmax, 32));                                  \
    if (!__all(rmax - mq <= 8.0f)) {                                           \
      const float mn = fmaxf(mq, rmax);                                        \
      const float al = exp2f(mq - mn);                                         \
      mq = mn; lq *= al;                                                       \
      _Pragma("unroll") for (int r = 0; r < 16; r++) {                         \
        const float ar = __shfl(al, CROW(r));                                  \
        _Pragma("unroll") for (int d = 0; d < 4; d++) accO[d][r] *= ar;        \
      }                                                                        \
    }                                                                          \
    float p[32]; float rsum = 0.f;                                             \
    _Pragma("unroll") for (int r = 0; r < 16; r++) {                           \
      p[r] = exp2f(s0[r] - mq); rsum += p[r];                                  \
      p[16 + r] = exp2f(s1[r] - mq); rsum += p[16 + r];                        \
    }                                                                          \
    rsum += __shfl_xor(rsum, 32);                                              \
    lq += rsum;                                                                \
    bf16x8 pa[4];                                                              \
    _Pragma("unroll") for (int kb = 0; kb < 2; kb++) {                         \
      unsigned A0, A1, A2, A3, A4, A5, A6, A7;                                 \
      const int bp = kb * 16;                                                  \
      asm("v_cvt_pk_bf16_f32 %0, %1, %2" : "=v"(A0) : "v"(p[bp+0]), "v"(p[bp+1])); \
      asm("v_cvt_pk_bf16_f32 %0, %1, %2" : "=v"(A1) : "v"(p[bp+2]), "v"(p[bp+3])); \
      asm("v_cvt_pk_bf16_f32 %0, %1, %2" : "=v"(A2) : "v"(p[bp+4]), "v"(p[bp+5])); \
      asm("v_cvt_pk_bf16_f32 %0, %1, %2" : "=v"(A3) : "v"(p[bp+6]), "v"(p[bp+7])); \
      asm("v_cvt_pk_bf16_f32 %0, %1, %2" : "=v"(A4) : "v"(p[bp+8]), "v"(p[bp+9])); \
      asm("v_cvt_pk_bf16_f32 %0, %1, %2" : "=v"(A5) : "v"(p[bp+10]), "v"(p[bp+11])); \
      asm("v_cvt_pk_bf16_f32 %0, %1, %2" : "=v"(A6) : "v"(p[bp+12]), "v"(p[bp+13])); \
      asm("v_cvt_pk_bf16_f32 %0, %1, %2" : "=v"(A7) : "v"(p[bp+14]), "v"(p[bp+15])); \
      asm("v_permlane32_swap_b32 %0, %1" : "+v"(A0), "+v"(A2));                \
      asm("v_permlane32_swap_b32 %0, %1" : "+v"(A1), "+v"(A3));                \
      asm("v_permlane32_swap_b32 %0, %1" : "+v"(A4), "+v"(A6));                \
      asm("v_permlane32_swap_b32 %0, %1" : "+v"(A5), "+v"(A7));                \
      union { unsigned u[4]; bf16x8 v; } f0, f1;                               \
      f0.u[0] = A0; f0.u[1] = A1; f0.u[2] = A2; f0.u[3] = A3;                  \
      f1.u[0] = A4; f1.u[1] = A5; f1.u[2] = A6; f1.u[3] = A7;                  \
      pa[kb * 2] = f0.v; pa[kb * 2 + 1] = f1.v;                                \
    }                                                                          \
    _Pragma("unroll") for (int c = 0; c < 4; c++) {                            \
      _Pragma("unroll") for (int d = 0; d < 4; d++) {                          \
        const int vrow = d * 32 + l31;                                         \
        const bf16x8 vb = *(const bf16x8*)((const char*)(VS) + vrow * 128 +    \
                          ((c * 32 + hi * 16) ^ ((vrow & 7) << 4)));           \
        accO[d] = __builtin_amdgcn_mfma_f32_32x32x16_bf16(pa[c], vb, accO[d], 0, 0, 0); \
      }                                                                        \
    }                                                                          \
  }

__global__ __launch_bounds__(256, 2) void attn_k(
    const u16* __restrict__ qbuf, const u16* __restrict__ kbuf,
    const u16* __restrict__ vT, u16* __restrict__ obuf) {
  const int flat = blockIdx.y * gridDim.x + blockIdx.x;   // 1024 total
  const int swz = (flat & 7) * 128 + (flat >> 3);         // XCD chunks of 128
  const int bh = swz >> 5, b = bh >> 4, h = bh & 15;
  const int q0 = (swz & 31) * 128;
  const int tid = threadIdx.x, lane = tid & 63, wid = tid >> 6;
  const int l31 = lane & 31, hi = lane >> 5;

  __shared__ __align__(16) u16 Ks0[64 * 128];
  __shared__ __align__(16) u16 Ks1[64 * 128];
  __shared__ __align__(16) u16 Vs0[128 * 64];
  __shared__ __align__(16) u16 Vs1[128 * 64];

  const size_t qkbase = (size_t)(b * SEQ) * DIMC + h * HD;
  const u16* Qp = qbuf + qkbase;
  const u16* Kp = kbuf + qkbase;
  const u16* Vp = vT + (size_t)(b * DIMC + h * HD) * SEQ;

  // Q fragments (B operand): lane l31 = q row, k-chunk j: d = 16j + hi*8 + e
  bf16x8 qf[8];
  const int qrow = q0 + wid * 32 + l31;
#pragma unroll
  for (int j = 0; j < 8; ++j)
    qf[j] = *(const bf16x8*)(Qp + (size_t)qrow * DIMC + j * 16 + hi * 8);

  float mq = -1e30f, lq = 0.f;
  f32x16 accO[4];
#pragma unroll
  for (int d = 0; d < 4; d++)
#pragma unroll
    for (int i = 0; i < 16; i++) accO[d][i] = 0.f;

  STAGE(Ks0, Vs0, 0);
  __syncthreads();

#pragma unroll 1
  for (int t = 0; t < SEQ / 64; t += 2) {
    STAGE(Ks1, Vs1, (t + 1) * 64);
    COMPUTE(Ks0, Vs0);
    __syncthreads();
    if (t + 2 < SEQ / 64) STAGE(Ks0, Vs0, (t + 2) * 64);
    COMPUTE(Ks1, Vs1);
    __syncthreads();
  }

  const float linv = 1.0f / lq;
  u16* Op = obuf + (size_t)(b * SEQ + q0 + wid * 32) * DIMC + h * HD;
#pragma unroll
  for (int r = 0; r < 16; r++) {
    const float lr = __shfl(linv, CROW(r));
    const int orow = CROW(r);
#pragma unroll
    for (int d = 0; d < 4; d++)
      Op[(size_t)orow * DIMC + d * 32 + l31] = f2bf(accO[d][r] * lr);
  }
}

// ---------------- launch ----------------
extern "C" void kernel_launch(void* const* d_in, const int* in_sizes, int n_in,
                              void* d_out, int out_size, void* d_ws, size_t ws_size,
                              hipStream_t stream) {
  const float* x     = (const float*)d_in[0];
  const float* freqs = (const float*)d_in[2];
  const float* wq = (const float*)d_in[3];
  const float* bq = (const float*)d_in[4];
  const float* wk = (const float*)d_in[5];
  const float* bk = (const float*)d_in[6];
  const float* wv = (const float*)d_in[7];
  const float* bv = (const float*)d_in[8];
  const float* wo = (const float*)d_in[9];
  const float* bo = (const float*)d_in[10];
  const float* gq = (const float*)d_in[11];
  const float* gk = (const float*)d_in[12];

  const size_t WS = (size_t)DIMC * DIMC;       // weight elems
  const size_t QS = (size_t)MTOK * DIMC;       // activation elems
  char* ws = (char*)d_ws;
  u16* xb  = (u16*)ws;  ws += QS * 2;
  u16* wb  = (u16*)ws;  ws += 4 * WS * 2;
  u16* qkv = (u16*)ws;  ws += 3 * QS * 2;
  u16* vT  = (u16*)ws;  ws += QS * 2;
  u16* ob  = (u16*)ws;  ws += QS * 2;

  cast_bf16_k<<<(int)(QS / 1024), 256, 0, stream>>>(x, xb, (int)QS);
  cast_bf16_k<<<(int)(WS / 1024), 256, 0, stream>>>(wq, wb + 0 * WS, (int)WS);
  cast_bf16_k<<<(int)(WS / 1024), 256, 0, stream>>>(wk, wb + 1 * WS, (int)WS);
  cast_bf16_k<<<(int)(WS / 1024), 256, 0, stream>>>(wv, wb + 2 * WS, (int)WS);
  cast_bf16_k<<<(int)(WS / 1024), 256, 0, stream>>>(wo, wb + 3 * WS, (int)WS);

  dim3 ggrid(DIMC / 128, MTOK / 128);
  gemm_bt_k<false><<<ggrid, 256, 0, stream>>>(xb, wb + 0 * WS, bq, qkv + 0 * QS, DIMC, DIMC);
  gemm_bt_k<false><<<ggrid, 256, 0, stream>>>(xb, wb + 1 * WS, bk, qkv + 1 * QS, DIMC, DIMC);
  gemm_bt_k<false><<<ggrid, 256, 0, stream>>>(xb, wb + 2 * WS, bv, qkv + 2 * QS, DIMC, DIMC);

  rmsrope_k<<<MTOK, 256, 0, stream>>>(qkv, gq, gk, freqs);
  vtrans_k<<<dim3(SEQ / 64, DIMC / 64, BSZ), 256, 0, stream>>>(qkv + 2 * QS, vT);
  attn_k<<<dim3(SEQ / 128, BSZ * NH), 256, 0, stream>>>(qkv, qkv + 1 * QS, vT, ob);

  gemm_bt_k<true><<<ggrid, 256, 0, stream>>>(ob, wb + 3 * WS, bo, d_out, DIMC, DIMC);
}

// Round 5
// 713.281 us; speedup vs baseline: 2.1724x; 1.1449x over previous
//
#include <hip/hip_runtime.h>
#include <hip/hip_bf16.h>

typedef unsigned short u16;
typedef __bf16 bf16x8 __attribute__((ext_vector_type(8)));
typedef float f32x4 __attribute__((ext_vector_type(4)));
typedef float f32x16 __attribute__((ext_vector_type(16)));

#define DIMC  2048
#define NH    16
#define HD    128
#define BSZ   2
#define SEQ   4096
#define MTOK  (BSZ*SEQ)   /* 8192 tokens */

// scale * log2(e): folded into Q at rmsrope time
#define SCALE_L2E (0.08838834764831845f * 1.4426950408889634f)

__device__ __forceinline__ u16 f2bf(float f) {
  unsigned u = __float_as_uint(f);
  u += 0x7fff + ((u >> 16) & 1);   // RTNE
  return (u16)(u >> 16);
}
__device__ __forceinline__ float bf2f(u16 b) {
  return __uint_as_float(((unsigned)b) << 16);
}

__device__ __forceinline__ void gload_lds16(const void* g, void* l) {
  __builtin_amdgcn_global_load_lds(
      (const __attribute__((address_space(1))) void*)g,
      (__attribute__((address_space(3))) void*)l, 16, 0, 0);
}

#define BAR() __builtin_amdgcn_s_barrier()
#define ASM_VMCNT(n) do { asm volatile("s_waitcnt vmcnt(" #n ")" ::: "memory"); \
                          __builtin_amdgcn_sched_barrier(0); } while (0)
#define ASM_LGK0()   do { asm volatile("s_waitcnt lgkmcnt(0)" ::: "memory");    \
                          __builtin_amdgcn_sched_barrier(0); } while (0)

// ---------------- cast f32 -> bf16 ----------------
__global__ __launch_bounds__(256) void cast_bf16_k(const float* __restrict__ in,
                                                   u16* __restrict__ out, int n) {
  int i = (blockIdx.x * 256 + threadIdx.x) * 4;
  if (i >= n) return;
  float4 v = *(const float4*)(in + i);
  ushort4 o;
  o.x = f2bf(v.x); o.y = f2bf(v.y); o.z = f2bf(v.z); o.w = f2bf(v.w);
  *(ushort4*)(out + i) = o;
}

// ---------------- 256x256 8-phase GEMM (T2+T3+T4+T5) ----------------
// C[m,n] = sum_k A[m,k]*Bt[n,k] + bias[n].  8 waves (2M x 4N), BK=64,
// 2 K-tiles/iter, 128 KiB LDS double-buffer, counted vmcnt(4) at ph4/ph8,
// B-fragments hoisted to regs at ph1/ph5, LDS rows swizzled byte^=(row&7)<<4.
// blockIdx.z selects (weight, bias, out) slice for fused QKV.

// stage half-tile h of K-tile kt into LDS buffer d (A or B variant)
#define STG_A(d, kt, h)                                                        \
  { const u16* s_ = Ag + (size_t)(h) * khalf + (size_t)(kt) * 64;              \
    gload_lds16(s_ + at0, (u16*)As[d][h] + tid * 8);                           \
    gload_lds16(s_ + at1, (u16*)As[d][h] + (tid + 512) * 8); }
#define STG_B(d, kt, h)                                                        \
  { const u16* s_ = Bg + (size_t)(h) * khalf + (size_t)(kt) * 64;              \
    gload_lds16(s_ + at0, (u16*)Bs[d][h] + tid * 8);                           \
    gload_lds16(s_ + at1, (u16*)Bs[d][h] + (tid + 512) * 8); }

#define GPHASE(bb, q, STAGE_CODE, TAIL_CODE)                                   \
  {                                                                            \
    if ((q) == 0) {                                                            \
      _Pragma("unroll") for (int fc = 0; fc < 4; fc++)                         \
        _Pragma("unroll") for (int ks = 0; ks < 2; ks++)                       \
          bfr[fc][ks] = *(const bf16x8*)((const char*)Bs[bb][wc >> 1] +        \
              rbB + fc * 2048 + colr[ks]);                                     \
    }                                                                          \
    _Pragma("unroll") for (int e = 0; e < 2; e++)                              \
      _Pragma("unroll") for (int ks = 0; ks < 2; ks++)                         \
        afr[e][ks] = *(const bf16x8*)((const char*)As[bb][wr] +                \
            rbA + (2 * (q) + e) * 2048 + colr[ks]);                            \
    STAGE_CODE;                                                                \
    BAR();                                                                     \
    ASM_LGK0();                                                                \
    __builtin_amdgcn_s_setprio(1);                                             \
    _Pragma("unroll") for (int e = 0; e < 2; e++)                              \
      _Pragma("unroll") for (int fc = 0; fc < 4; fc++)                         \
        _Pragma("unroll") for (int ks = 0; ks < 2; ks++)                       \
          acc[2 * (q) + e][fc] = __builtin_amdgcn_mfma_f32_16x16x32_bf16(      \
              afr[e][ks], bfr[fc][ks], acc[2 * (q) + e][fc], 0, 0, 0);         \
    __builtin_amdgcn_s_setprio(0);                                             \
    TAIL_CODE;                                                                 \
    BAR();                                                                     \
    __builtin_amdgcn_sched_barrier(0);                                         \
  }

template<bool OUT_F32>
__global__ __launch_bounds__(512, 2) void gemm256_k(
    const u16* __restrict__ A, const u16* __restrict__ Bt,
    const float* __restrict__ b0, const float* __restrict__ b1,
    const float* __restrict__ b2, void* __restrict__ Cout,
    size_t wstride, size_t ostride, int Ndim, int Kdim) {
  __shared__ __align__(16) u16 As[2][2][128 * 64];
  __shared__ __align__(16) u16 Bs[2][2][128 * 64];
  const int tid = threadIdx.x;
  const int lane = tid & 63, wid = tid >> 6;
  const int wr = wid >> 2, wc = wid & 3;          // 2M x 4N waves
  const int l15 = lane & 15, lg = lane >> 4;
  const int z = blockIdx.z;

  const u16* W = Bt + (size_t)z * wstride;
  const float* bias = (z == 0) ? b0 : (z == 1 ? b1 : b2);

  // XCD-aware swizzle over the 256-block x/y grid (8 x 32)
  const int flat = blockIdx.y * gridDim.x + blockIdx.x;
  const int cpx = (gridDim.x * gridDim.y) >> 3;
  const int swz = (flat & 7) * cpx + (flat >> 3);
  const int bn = (swz % gridDim.x) * 256;
  const int bm = (swz / gridDim.x) * 256;

  const u16* Ag = A + (size_t)bm * Kdim;
  const u16* Bg = W + (size_t)bn * Kdim;
  const size_t khalf = (size_t)128 * Kdim;

  // per-thread staging offsets (chunk c = tid, tid+512; row=c>>3, cc=c&7)
  const int r0 = tid >> 3, cc0 = tid & 7;
  const size_t at0 = (size_t)r0 * Kdim + (size_t)((cc0 ^ (r0 & 7)) * 8);
  const size_t at1 = at0 + (size_t)64 * Kdim;

  // fragment-read address terms (swizzle XOR is lane-constant)
  const int swzl = (l15 & 7) << 4;
  int colr[2];
  colr[0] = (0 * 64 + lg * 16) ^ swzl;
  colr[1] = (1 * 64 + lg * 16) ^ swzl;
  const int rbA = l15 * 128;
  const int rbB = (wc & 1) * 8192 + l15 * 128;

  f32x4 acc[8][4];
#pragma unroll
  for (int i = 0; i < 8; i++)
#pragma unroll
    for (int j = 0; j < 4; j++) acc[i][j] = f32x4{0.f, 0.f, 0.f, 0.f};
  bf16x8 bfr[4][2], afr[2][2];

  // prologue: A(0), B(0), B(1); wait A(0)+B(0) landed (B(1) in flight)
  STG_A(0, 0, 0); STG_A(0, 0, 1);
  STG_B(0, 0, 0); STG_B(0, 0, 1);
  STG_B(1, 1, 0); STG_B(1, 1, 1);
  ASM_VMCNT(4);
  BAR();

  const int niter = Kdim / 128 - 1;
#pragma unroll 1
  for (int k = 0; k < niter; ++k) {
    const int t = 2 * k;
    GPHASE(0, 0, STG_A(1, t + 1, 0), (void)0);
    GPHASE(0, 1, STG_A(1, t + 1, 1), (void)0);
    GPHASE(0, 2, STG_B(0, t + 2, 0), (void)0);
    GPHASE(0, 3, STG_B(0, t + 2, 1), ASM_VMCNT(4));
    GPHASE(1, 0, STG_A(0, t + 2, 0), (void)0);
    GPHASE(1, 1, STG_A(0, t + 2, 1), (void)0);
    GPHASE(1, 2, STG_B(1, t + 3, 0), (void)0);
    GPHASE(1, 3, STG_B(1, t + 3, 1), ASM_VMCNT(4));
  }
  // epilogue iteration: K-tiles Kdim/64-2 (buf0), Kdim/64-1 (buf1)
  {
    const int tl = Kdim / 64 - 1;
    GPHASE(0, 0, STG_A(1, tl, 0), (void)0);
    GPHASE(0, 1, STG_A(1, tl, 1), (void)0);
    GPHASE(0, 2, (void)0, (void)0);
    GPHASE(0, 3, (void)0, ASM_VMCNT(0));
    GPHASE(1, 0, (void)0, (void)0);
    GPHASE(1, 1, (void)0, (void)0);
    GPHASE(1, 2, (void)0, (void)0);
    GPHASE(1, 3, (void)0, (void)0);
  }

  // epilogue: C/D layout col=lane&15, row=(lane>>4)*4+reg
#pragma unroll
  for (int fc = 0; fc < 4; fc++) {
    const int cj = bn + wc * 64 + fc * 16 + l15;
    const float bv = bias[cj];
#pragma unroll
    for (int fr = 0; fr < 8; fr++) {
      const int row0 = bm + wr * 128 + fr * 16 + lg * 4;
#pragma unroll
      for (int r = 0; r < 4; r++) {
        float v = acc[fr][fc][r] + bv;
        if (OUT_F32)
          ((float*)Cout)[(size_t)z * ostride + (size_t)(row0 + r) * Ndim + cj] = v;
        else
          ((u16*)Cout)[(size_t)z * ostride + (size_t)(row0 + r) * Ndim + cj] = f2bf(v);
      }
    }
  }
}

// ---------------- fused RMSNorm + RoPE (in-place on q,k; bf16 storage) ----------------
__global__ __launch_bounds__(256) void rmsrope_k(
    u16* __restrict__ qk, const float* __restrict__ gq, const float* __restrict__ gk,
    const float* __restrict__ freqs) {
  const int t = blockIdx.x;        // token
  const int s = t & (SEQ - 1);
  const int tid = threadIdx.x;
  __shared__ float red[8];

  for (int which = 0; which < 2; ++which) {
    u16* row = qk + (size_t)which * ((size_t)MTOK * DIMC) + (size_t)t * DIMC;
    const float* g = which ? gk : gq;
    const float oscale = which ? 1.0f : SCALE_L2E;
    uint4 raw = *(const uint4*)(row + tid * 8);
    const u16* rb = (const u16*)&raw;
    float v[8], ss = 0.f;
#pragma unroll
    for (int e = 0; e < 8; e++) { v[e] = bf2f(rb[e]); ss += v[e] * v[e]; }
#pragma unroll
    for (int m = 1; m < 64; m <<= 1) ss += __shfl_xor(ss, m);
    if ((tid & 63) == 0) red[which * 4 + (tid >> 6)] = ss;
    __syncthreads();
    float tot = red[which * 4] + red[which * 4 + 1] + red[which * 4 + 2] + red[which * 4 + 3];
    float rms = rsqrtf(tot * (1.0f / (float)DIMC) + 1e-6f);
    const int ch0 = tid * 8;
    const int d0 = ch0 & (HD - 1);
    u16 ob[8];
#pragma unroll
    for (int p = 0; p < 4; p++) {
      float fr = freqs[s * (HD / 2) + (d0 >> 1) + p];
      float cs = cosf(fr), sn = sinf(fr);
      float e = v[2 * p] * rms * g[ch0 + 2 * p];
      float o = v[2 * p + 1] * rms * g[ch0 + 2 * p + 1];
      ob[2 * p]     = f2bf((e * cs - o * sn) * oscale);
      ob[2 * p + 1] = f2bf((e * sn + o * cs) * oscale);
    }
    *(uint4*)(row + tid * 8) = *(const uint4*)ob;
    __syncthreads();
  }
}

// ---------------- transpose V: v[t][c] -> vT[(b*2048+c)][s] ----------------
__global__ __launch_bounds__(256) void vtrans_k(const u16* __restrict__ v, u16* __restrict__ vT) {
  __shared__ u16 tile[64][72];
  const int s0 = blockIdx.x * 64, c0 = blockIdx.y * 64, b = blockIdx.z;
  const int tid = threadIdx.x;
  const int rr = tid >> 3, cc8 = (tid & 7) * 8;
#pragma unroll
  for (int it = 0; it < 2; ++it) {
    int si = it * 32 + rr;
    uint4 d = *(const uint4*)(v + ((size_t)(b * SEQ + s0 + si)) * DIMC + c0 + cc8);
    const u16* dp = (const u16*)&d;
#pragma unroll
    for (int e = 0; e < 8; e++) tile[si][cc8 + e] = dp[e];
  }
  __syncthreads();
#pragma unroll
  for (int it = 0; it < 2; ++it) {
    int ci = it * 32 + rr;
    u16 buf[8];
#pragma unroll
    for (int e = 0; e < 8; e++) buf[e] = tile[cc8 + e][ci];
    *(uint4*)(vT + ((size_t)(b * DIMC + c0 + ci)) * SEQ + s0 + cc8) = *(const uint4*)buf;
  }
}

// ---------------- flash attention: 32x32 swapped-QK^T, in-register softmax ----
#define STAGE(KS, VS, kv0)                                                     \
  _Pragma("unroll") for (int it = 0; it < 4; ++it) {                           \
    const int c = it * 256 + tid;                                              \
    { const int rr = c >> 4, ss = c & 15;                                      \
      gload_lds16(Kp + (size_t)((kv0) + rr) * DIMC + ((ss ^ (rr & 15)) * 8),   \
                  (u16*)(KS) + c * 8); }                                       \
    { const int rr = c >> 3, ss = c & 7;                                       \
      gload_lds16(Vp + (size_t)rr * SEQ + (kv0) + ((ss ^ (rr & 7)) * 8),       \
                  (u16*)(VS) + c * 8); }                                       \
  }

#define CROW(r) (((r) & 3) + 8 * ((r) >> 2) + 4 * hi)

#define COMPUTE(KS, VS)                                                        \
  {                                                                            \
    f32x16 s0, s1;                                                             \
    _Pragma("unroll") for (int i = 0; i < 16; i++) { s0[i] = 0.f; s1[i] = 0.f; } \
    _Pragma("unroll") for (int j = 0; j < 8; ++j) {                            \
      const int byt = (j * 32 + hi * 16);                                      \
      const bf16x8 k0 = *(const bf16x8*)((const char*)(KS) + l31 * 256 +       \
                        (byt ^ ((l31 & 15) << 4)));                            \
      const bf16x8 k1 = *(const bf16x8*)((const char*)(KS) + (32 + l31) * 256 + \
                        (byt ^ ((l31 & 15) << 4)));                            \
      s0 = __builtin_amdgcn_mfma_f32_32x32x16_bf16(k0, qf[j], s0, 0, 0, 0);    \
      s1 = __builtin_amdgcn_mfma_f32_32x32x16_bf16(k1, qf[j], s1, 0, 0, 0);    \
    }                                                                          \
    float rmax = s0[0];                                                        \
    _Pragma("unroll") for (int r = 1; r < 16; r++) rmax = fmaxf(rmax, s0[r]);  \
    _Pragma("unroll") for (int r = 0; r < 16; r++) rmax = fmaxf(rmax, s1[r]);  \
    rmax = fmaxf(rmax, __shfl_xor(rmax, 32));                                  \
    if (!__all(rmax - mq <= 8.0f)) {                                           \
      const float mn = fmaxf(mq, rmax);                                        \
      const float al = exp2f(mq - mn);                                         \
      mq = mn; lq *= al;                                                       \
      _Pragma("unroll") for (int r = 0; r < 16; r++) {                         \
        const float ar = __shfl(al, CROW(r));                                  \
        _Pragma("unroll") for (int d = 0; d < 4; d++) accO[d][r] *= ar;        \
      }                                                                        \
    }                                                                          \
    float p[32]; float rsum = 0.f;                                             \
    _Pragma("unroll") for (int r = 0; r < 16; r++) {                           \
      p[r] = exp2f(s0[r] - mq); rsum += p[r];                                  \
      p[16 + r] = exp2f(s1[r] - mq); rsum += p[16 + r];                        \
    }                                                                          \
    rsum += __shfl_xor(rsum, 32);                                              \
    lq += rsum;                                                                \
    bf16x8 pa[4];                                                              \
    _Pragma("unroll") for (int kb = 0; kb < 2; kb++) {                         \
      unsigned A0, A1, A2, A3, A4, A5, A6, A7;                                 \
      const int bp = kb * 16;                                                  \
      asm("v_cvt_pk_bf16_f32 %0, %1, %2" : "=v"(A0) : "v"(p[bp+0]), "v"(p[bp+1])); \
      asm("v_cvt_pk_bf16_f32 %0, %1, %2" : "=v"(A1) : "v"(p[bp+2]), "v"(p[bp+3])); \
      asm("v_cvt_pk_bf16_f32 %0, %1, %2" : "=v"(A2) : "v"(p[bp+4]), "v"(p[bp+5])); \
      asm("v_cvt_pk_bf16_f32 %0, %1, %2" : "=v"(A3) : "v"(p[bp+6]), "v"(p[bp+7])); \
      asm("v_cvt_pk_bf16_f32 %0, %1, %2" : "=v"(A4) : "v"(p[bp+8]), "v"(p[bp+9])); \
      asm("v_cvt_pk_bf16_f32 %0, %1, %2" : "=v"(A5) : "v"(p[bp+10]), "v"(p[bp+11])); \
      asm("v_cvt_pk_bf16_f32 %0, %1, %2" : "=v"(A6) : "v"(p[bp+12]), "v"(p[bp+13])); \
      asm("v_cvt_pk_bf16_f32 %0, %1, %2" : "=v"(A7) : "v"(p[bp+14]), "v"(p[bp+15])); \
      asm("v_permlane32_swap_b32 %0, %1" : "+v"(A0), "+v"(A2));                \
      asm("v_permlane32_swap_b32 %0, %1" : "+v"(A1), "+v"(A3));                \
      asm("v_permlane32_swap_b32 %0, %1" : "+v"(A4), "+v"(A6));                \
      asm("v_permlane32_swap_b32 %0, %1" : "+v"(A5), "+v"(A7));                \
      union { unsigned u[4]; bf16x8 v; } f0, f1;                               \
      f0.u[0] = A0; f0.u[1] = A1; f0.u[2] = A2; f0.u[3] = A3;                  \
      f1.u[0] = A4; f1.u[1] = A5; f1.u[2] = A6; f1.u[3] = A7;                  \
      pa[kb * 2] = f0.v; pa[kb * 2 + 1] = f1.v;                                \
    }                                                                          \
    _Pragma("unroll") for (int c = 0; c < 4; c++) {                            \
      _Pragma("unroll") for (int d = 0; d < 4; d++) {                          \
        const int vrow = d * 32 + l31;                                         \
        const bf16x8 vb = *(const bf16x8*)((const char*)(VS) + vrow * 128 +    \
                          ((c * 32 + hi * 16) ^ ((vrow & 7) << 4)));           \
        accO[d] = __builtin_amdgcn_mfma_f32_32x32x16_bf16(pa[c], vb, accO[d], 0, 0, 0); \
      }                                                                        \
    }                                                                          \
  }

__global__ __launch_bounds__(256, 2) void attn_k(
    const u16* __restrict__ qbuf, const u16* __restrict__ kbuf,
    const u16* __restrict__ vT, u16* __restrict__ obuf) {
  const int flat = blockIdx.y * gridDim.x + blockIdx.x;   // 1024 total
  const int swz = (flat & 7) * 128 + (flat >> 3);         // XCD chunks of 128
  const int bh = swz >> 5, b = bh >> 4, h = bh & 15;
  const int q0 = (swz & 31) * 128;
  const int tid = threadIdx.x, lane = tid & 63, wid = tid >> 6;
  const int l31 = lane & 31, hi = lane >> 5;

  __shared__ __align__(16) u16 Ks0[64 * 128];
  __shared__ __align__(16) u16 Ks1[64 * 128];
  __shared__ __align__(16) u16 Vs0[128 * 64];
  __shared__ __align__(16) u16 Vs1[128 * 64];

  const size_t qkbase = (size_t)(b * SEQ) * DIMC + h * HD;
  const u16* Qp = qbuf + qkbase;
  const u16* Kp = kbuf + qkbase;
  const u16* Vp = vT + (size_t)(b * DIMC + h * HD) * SEQ;

  bf16x8 qf[8];
  const int qrow = q0 + wid * 32 + l31;
#pragma unroll
  for (int j = 0; j < 8; ++j)
    qf[j] = *(const bf16x8*)(Qp + (size_t)qrow * DIMC + j * 16 + hi * 8);

  float mq = -1e30f, lq = 0.f;
  f32x16 accO[4];
#pragma unroll
  for (int d = 0; d < 4; d++)
#pragma unroll
    for (int i = 0; i < 16; i++) accO[d][i] = 0.f;

  STAGE(Ks0, Vs0, 0);
  __syncthreads();

#pragma unroll 1
  for (int t = 0; t < SEQ / 64; t += 2) {
    STAGE(Ks1, Vs1, (t + 1) * 64);
    COMPUTE(Ks0, Vs0);
    __syncthreads();
    if (t + 2 < SEQ / 64) STAGE(Ks0, Vs0, (t + 2) * 64);
    COMPUTE(Ks1, Vs1);
    __syncthreads();
  }

  const float linv = 1.0f / lq;
  u16* Op = obuf + (size_t)(b * SEQ + q0 + wid * 32) * DIMC + h * HD;
#pragma unroll
  for (int r = 0; r < 16; r++) {
    const float lr = __shfl(linv, CROW(r));
    const int orow = CROW(r);
#pragma unroll
    for (int d = 0; d < 4; d++)
      Op[(size_t)orow * DIMC + d * 32 + l31] = f2bf(accO[d][r] * lr);
  }
}

// ---------------- launch ----------------
extern "C" void kernel_launch(void* const* d_in, const int* in_sizes, int n_in,
                              void* d_out, int out_size, void* d_ws, size_t ws_size,
                              hipStream_t stream) {
  const float* x     = (const float*)d_in[0];
  const float* freqs = (const float*)d_in[2];
  const float* wq = (const float*)d_in[3];
  const float* bq = (const float*)d_in[4];
  const float* wk = (const float*)d_in[5];
  const float* bk = (const float*)d_in[6];
  const float* wv = (const float*)d_in[7];
  const float* bv = (const float*)d_in[8];
  const float* wo = (const float*)d_in[9];
  const float* bo = (const float*)d_in[10];
  const float* gq = (const float*)d_in[11];
  const float* gk = (const float*)d_in[12];

  const size_t WS = (size_t)DIMC * DIMC;       // weight elems
  const size_t QS = (size_t)MTOK * DIMC;       // activation elems
  char* ws = (char*)d_ws;
  u16* xb  = (u16*)ws;  ws += QS * 2;
  u16* wb  = (u16*)ws;  ws += 4 * WS * 2;
  u16* qkv = (u16*)ws;  ws += 3 * QS * 2;
  u16* vT  = (u16*)ws;  ws += QS * 2;
  u16* ob  = (u16*)ws;  ws += QS * 2;

  cast_bf16_k<<<(int)(QS / 1024), 256, 0, stream>>>(x, xb, (int)QS);
  cast_bf16_k<<<(int)(WS / 1024), 256, 0, stream>>>(wq, wb + 0 * WS, (int)WS);
  cast_bf16_k<<<(int)(WS / 1024), 256, 0, stream>>>(wk, wb + 1 * WS, (int)WS);
  cast_bf16_k<<<(int)(WS / 1024), 256, 0, stream>>>(wv, wb + 2 * WS, (int)WS);
  cast_bf16_k<<<(int)(WS / 1024), 256, 0, stream>>>(wo, wb + 3 * WS, (int)WS);

  // fused QKV: z selects weight/bias/output slice
  gemm256_k<false><<<dim3(DIMC / 256, MTOK / 256, 3), 512, 0, stream>>>(
      xb, wb, bq, bk, bv, qkv, WS, QS, DIMC, DIMC);

  rmsrope_k<<<MTOK, 256, 0, stream>>>(qkv, gq, gk, freqs);
  vtrans_k<<<dim3(SEQ / 64, DIMC / 64, BSZ), 256, 0, stream>>>(qkv + 2 * QS, vT);
  attn_k<<<dim3(SEQ / 128, BSZ * NH), 256, 0, stream>>>(qkv, qkv + 1 * QS, vT, ob);

  gemm256_k<true><<<dim3(DIMC / 256, MTOK / 256, 1), 512, 0, stream>>>(
      ob, wb + 3 * WS, bo, bo, bo, d_out, 0, 0, DIMC, DIMC);
}